// Round 8
// baseline (374.276 us; speedup 1.0000x reference)
//
#include <hip/hip_runtime.h>
#include <hip/hip_bf16.h>

typedef unsigned short u16;
typedef unsigned int u32;
typedef __attribute__((ext_vector_type(8))) short short8;
typedef __attribute__((ext_vector_type(4))) float floatx4;

__device__ inline float bf2f(u16 u) { union { u32 i; float f; } v; v.i = ((u32)u) << 16; return v.f; }
__device__ inline u16 f2bf(float f) {
    union { float f; u32 i; } v; v.f = f;
    u32 lsb = (v.i >> 16) & 1u;
    v.i += 0x7fffu + lsb;              // round-to-nearest-even
    return (u16)(v.i >> 16);
}

__device__ inline uint4 pack8(float4 a, float4 b) {
    uint4 q;
    q.x = (u32)f2bf(a.x) | ((u32)f2bf(a.y) << 16);
    q.y = (u32)f2bf(a.z) | ((u32)f2bf(a.w) << 16);
    q.z = (u32)f2bf(b.x) | ((u32)f2bf(b.y) << 16);
    q.w = (u32)f2bf(b.z) | ((u32)f2bf(b.w) << 16);
    return q;
}

__device__ inline void ld8(u16* dst, const float* src) {
    const float4 a = *(const float4*)src;
    const float4 b = *(const float4*)(src + 4);
    *(uint4*)dst = pack8(a, b);
}

// async 16B global->LDS DMA; ldst must be wave-uniform (dest = ldst + lane*16)
__device__ inline void async16(u16* ldst, const u16* gsrc) {
    __builtin_amdgcn_global_load_lds((const __attribute__((address_space(1))) u32*)gsrc,
                                     (__attribute__((address_space(3))) u32*)ldst, 16, 0, 0);
}

// counted vmcnt wait (never drain to 0 in the main loop - T4); "memory" clobber
// pins all memory ops (ds_read/global_load_lds) on the correct side.
template <int N> __device__ inline void waitvm() {
    static_assert(N == 0 || N == 2 || N == 3 || N == 4 || N == 6 || N == 8, "unsupported vmcnt");
    if constexpr (N == 0) asm volatile("s_waitcnt vmcnt(0)" ::: "memory");
    if constexpr (N == 2) asm volatile("s_waitcnt vmcnt(2)" ::: "memory");
    if constexpr (N == 3) asm volatile("s_waitcnt vmcnt(3)" ::: "memory");
    if constexpr (N == 4) asm volatile("s_waitcnt vmcnt(4)" ::: "memory");
    if constexpr (N == 6) asm volatile("s_waitcnt vmcnt(6)" ::: "memory");
    if constexpr (N == 8) asm volatile("s_waitcnt vmcnt(8)" ::: "memory");
}
__device__ inline void barrier_raw() {
    asm volatile("s_barrier" ::: "memory");
    __builtin_amdgcn_sched_barrier(0);      // pin schedule at the phase boundary
}
__device__ inline void waitlgkm0() {
    // rule #18: inline lgkmcnt wait must be followed by sched_barrier(0) or
    // hipcc may hoist register-only MFMAs above it (they ignore "memory").
    asm volatile("s_waitcnt lgkmcnt(0)" ::: "memory");
    __builtin_amdgcn_sched_barrier(0);
}

// ---------------------------------------------------------------------------
// NT GEMM: C[MxN] = A[MxK] @ B[NxK]^T, bf16 in / fp32 MFMA accum.
// 3-slot LDS ring, 2-ahead prefetch, counted vmcnt (T3/T4):
//   prologue: stage(0), stage(1)
//   iter i:   s_waitcnt vmcnt(PW)          // own tile-i DMAs done (i+1 flying)
//             s_barrier                    // publish: everyone's tile i done
//             stage(slot of i+2)           // overwrites slot of i-1: every
//                                          //   wave's compute(i-1) ds_reads
//                                          //   retired (lgkmcnt0) pre-barrier
//             ds_read frags; lgkmcnt(0); MFMA on slot of i
//   tail:     vmcnt(PW) / vmcnt(0) peeled iters.
// BM=64 for the latency-bound big GEMMs: slot 12KB -> 36.9KB LDS total ->
// 4 blocks/CU (vs 2-3 at BM=128). Occupancy (TLP) beats per-block depth here
// (r0 PMC: MfmaUtil 8%, Occupancy 31%, HBM 29% = latency-bound).
// Epilogue: chunked epis stage the fp32 C-tile through LDS in 64-row passes,
// emit 16-B coalesced chunks. Epi::kv: tiles with col0>=vbase stage TRANSPOSED
// (cs[col*68+row]) and emit j-contiguous chunks into Vt directly.
// Epi::ylim>=0: blocks with zh!=0 && blockIdx.y>=ylim exit early (sq fold).
// ---------------------------------------------------------------------------
template <int BM, int BN, class Epi>
__global__ __launch_bounds__(256) void gemm_nt(const u16* __restrict__ A, const u16* __restrict__ B,
                                               long sAz, long sBz, int lda, int ldb, int K, int zlog, Epi epi)
{
    constexpr int AELE = BM * 32, BELE = BN * 32;   // elements per matrix per slot
    constexpr int SLOT = AELE + BELE;
    constexpr int IA = BM / 64, IB = BN / 64;       // DMA issues per wave per stage
    constexpr int PW = IA + IB;                      // vmcnt ops per wave per stage
    constexpr bool STAGE = Epi::chunked;
    static_assert(!STAGE || BN == 128, "chunked epilogue assumes BN=128");
    constexpr int LDC = BN + 4;                      // fp32 staging stride
    constexpr size_t RB = sizeof(u16) * 3 * (size_t)SLOT;            // ring bytes
    constexpr size_t EBR = STAGE ? sizeof(float) * 64 * (size_t)LDC : 0;
    constexpr size_t EBV = (STAGE && Epi::kv) ? sizeof(float) * 128 * 68 : 0;
    constexpr size_t EB = EBR > EBV ? EBR : EBV;
    constexpr size_t LB = RB > EB ? RB : EB;
    __shared__ __align__(16) char smem[LB];
    u16* lds = (u16*)smem;
    const int tid  = threadIdx.x;
    const int lane = tid & 63;
    const int wave = tid >> 6;
    const int z    = blockIdx.z;
    const int zh   = z >> zlog;
    const int zk   = z & ((1 << zlog) - 1);
    if constexpr (Epi::ylim >= 0) {                  // sq fold: skip unused blocks
        if (zh != 0 && (int)blockIdx.y >= Epi::ylim) return;
    }
    const long row0 = (long)blockIdx.y * BM;
    const long col0 = (long)blockIdx.x * BN;
    const u16* Ab = A + (long)zh * sAz + row0 * lda + (long)zk * K;
    const u16* Bb = B + (long)zh * sBz + col0 * ldb + (long)zk * K;
    constexpr int WM = BM / 2, WN = BN / 2, TM = WM / 16, TN = WN / 16;
    const int wm = (wave >> 1) * WM;
    const int wn = (wave & 1) * WN;
    const int l15 = lane & 15;
    const int quad = lane >> 4;
    const int swz = (l15 >> 1) & 3;   // (row>>1)&3 for row = 16*t + l15

    floatx4 acc[TM][TN];
#pragma unroll
    for (int i = 0; i < TM; i++)
#pragma unroll
        for (int j = 0; j < TN; j++) acc[i][j] = (floatx4){0.f, 0.f, 0.f, 0.f};

    auto stage = [&](int slot, int ki) {
        const int k0 = ki << 5;
        u16* base = lds + slot * SLOT;
#pragma unroll
        for (int i2 = 0; i2 < IA; i2++) {
            int s = wave * (IA * 64) + i2 * 64 + lane;       // chunk slot
            int r = s >> 2, c = (s & 3) ^ ((r >> 1) & 3);
            async16(base + (wave * (IA * 64) + i2 * 64) * 8, Ab + (long)r * lda + k0 + c * 8);
        }
        u16* bbase = base + AELE;
#pragma unroll
        for (int i2 = 0; i2 < IB; i2++) {
            int s = wave * (IB * 64) + i2 * 64 + lane;
            int r = s >> 2, c = (s & 3) ^ ((r >> 1) & 3);
            async16(bbase + (wave * (IB * 64) + i2 * 64) * 8, Bb + (long)r * ldb + k0 + c * 8);
        }
    };

    auto compute = [&](int slot) {
        const u16* As = lds + slot * SLOT;
        const u16* Bs = As + AELE;
        short8 af[TM], bfr[TN];
#pragma unroll
        for (int t = 0; t < TM; t++)
            af[t] = *(const short8*)(As + (wm + t * 16 + l15) * 32 + (quad ^ swz) * 8);
#pragma unroll
        for (int t = 0; t < TN; t++)
            bfr[t] = *(const short8*)(Bs + (wn + t * 16 + l15) * 32 + (quad ^ swz) * 8);
        waitlgkm0();                     // frag reads retired before next barrier
#pragma unroll
        for (int i = 0; i < TM; i++)
#pragma unroll
            for (int j = 0; j < TN; j++)
                acc[i][j] = __builtin_amdgcn_mfma_f32_16x16x32_bf16(af[i], bfr[j], acc[i][j], 0, 0, 0);
    };

    const int nIter = K >> 5;                        // K >= 128 -> nIter >= 4
    stage(0, 0);
    stage(1, 1);
    int s0 = 0, s1 = 1, s2 = 2;                      // slots of tiles i, i+1, i+2
    for (int i = 0; i + 2 < nIter; i++) {
        waitvm<PW>();
        barrier_raw();
        stage(s2, i + 2);                            // overwrites slot of tile i-1
        compute(s0);
        int t = s0; s0 = s1; s1 = s2; s2 = t;
    }
    waitvm<PW>(); barrier_raw(); compute(s0);
    waitvm<0>();  barrier_raw(); compute(s1);

    if constexpr (STAGE) {
        float* cs = (float*)smem;
        constexpr int NP = BM / 64;                  // 64-row passes
        bool vtile = false;
        if constexpr (Epi::kv) vtile = (col0 >= Epi::vbase);
#pragma unroll
        for (int p = 0; p < NP; p++) {
            __syncthreads();                         // prev reads done before overwrite
            if (!vtile) {
                if ((wm >> 6) == p) {
                    const int lr0 = wm & 63;
#pragma unroll
                    for (int i = 0; i < TM; i++)
#pragma unroll
                        for (int j = 0; j < TN; j++)
#pragma unroll
                            for (int r = 0; r < 4; r++)
                                cs[(lr0 + i * 16 + quad * 4 + r) * LDC + wn + j * 16 + l15] = acc[i][j][r];
                }
                __syncthreads();
                constexpr int CPT = (64 * BN) / (256 * 8);   // 16-B chunks per thread
#pragma unroll
                for (int k = 0; k < CPT; k++) {
                    int g = k * 256 + tid;
                    int row = g >> 4, c8 = (g & 15) * 8;
                    const float* pp = cs + row * LDC + c8;
                    float4 a = *(const float4*)pp;
                    float4 b = *(const float4*)(pp + 4);
                    epi.chunk(zh, zk, (int)row0 + p * 64 + row, (int)col0 + c8, a, b);
                }
            }
            if constexpr (Epi::kv) {
                if (vtile) {
                    // transposed staging: cs[col*68 + row], float4 per lane
                    if ((wm >> 6) == p) {
                        const int lr0 = wm & 63;
#pragma unroll
                        for (int i = 0; i < TM; i++)
#pragma unroll
                            for (int j = 0; j < TN; j++)
                                *(float4*)&cs[(wn + j * 16 + l15) * 68 + lr0 + i * 16 + quad * 4] =
                                    (float4){acc[i][j][0], acc[i][j][1], acc[i][j][2], acc[i][j][3]};
                    }
                    __syncthreads();
#pragma unroll
                    for (int k = 0; k < 4; k++) {    // 128 cols x 8 row-groups
                        int q = k * 256 + tid;
                        int colL = q >> 3, rg = q & 7;
                        const float* pp = cs + colL * 68 + rg * 8;
                        float4 a = *(const float4*)pp;
                        float4 b = *(const float4*)(pp + 4);
                        epi.vchunk(zh, (int)row0 + p * 64 + rg * 8, (int)col0 + colL, a, b);
                    }
                }
            }
        }
    } else {
#pragma unroll
        for (int i = 0; i < TM; i++)
#pragma unroll
            for (int j = 0; j < TN; j++)
#pragma unroll
                for (int r = 0; r < 4; r++) {
                    int row = (int)row0 + wm + i * 16 + quad * 4 + r;
                    int col = (int)col0 + wn + j * 16 + l15;
                    epi(zh, zk, row, col, acc[i][j][r]);
                }
    }
}

// --- epilogues -------------------------------------------------------------
struct EpiSkSq {  // zh=0: sk = x@Wsk + bsk (rows 0..32767); zh=1: sq (rows 0..511)
    static constexpr bool chunked = true;
    static constexpr bool kv = false;
    static constexpr int vbase = 0;
    static constexpr int ylim = 8;     // zh=1 uses only blocks y<8
    u16* sk; u16* sq; const float* bsk; const float* bsq;
    __device__ void chunk(int zh, int, int row, int col, float4 a, float4 b) const {
        const float* bias = zh ? bsq : bsk;
        u16* C = zh ? sq : sk;
        const float4* bp = (const float4*)(bias + col);
        float4 b0 = bp[0], b1 = bp[1];
        a.x += b0.x; a.y += b0.y; a.z += b0.z; a.w += b0.w;
        b.x += b1.x; b.y += b1.y; b.z += b1.z; b.w += b1.w;
        *(uint4*)(C + (long)row * 128 + col) = pack8(a, b);
    }
};
struct EpiQKV {  // fused Q+KV projection. cols: [0,512) Qw (w-scaled);
                 // [512,1024) Kp; [1024,1536) Vt via transposed vchunk.
    static constexpr bool chunked = true;
    static constexpr bool kv = true;
    static constexpr int vbase = 1024;
    static constexpr int ylim = -1;
    u16* Qw; u16* Kp; u16* Vt; const float* w;
    __device__ void chunk(int, int, int row, int col, float4 a, float4 b) const {
        int r = row >> 9, i = row & 511;
        if (col < 512) {
            int h = col >> 6, d = col & 63;
            float s = w[((long)(i * 8 + h)) * 64 + r] * 0.125f;
            a.x *= s; a.y *= s; a.z *= s; a.w *= s;
            b.x *= s; b.y *= s; b.z *= s; b.w *= s;
            *(uint4*)(Qw + (long)h * 2097152 + (long)i * 4096 + r * 64 + d) = pack8(a, b);
        } else {
            int c = col - 512, h = c >> 6, d = c & 63;
            *(uint4*)(Kp + (long)h * 2097152 + (long)i * 4096 + r * 64 + d) = pack8(a, b);
        }
    }
    __device__ void vchunk(int, int row8, int col, float4 a, float4 b) const {
        // 8 packed values = global rows row8..row8+7 (same r, consecutive j)
        int r = row8 >> 9, j0 = row8 & 511;
        int c = col - vbase, h = c >> 6, d = c & 63;
        *(uint4*)(Vt + (long)h * 2097152 + ((long)r * 64 + d) * 512 + j0) = pack8(a, b);
    }
};
struct EpiDotsAtomic {  // fallback: dots[zh][row][col] += v (pb resident), fp32
    static constexpr bool chunked = false;
    static constexpr bool kv = false;
    static constexpr int vbase = 0;
    static constexpr int ylim = -1;
    float* pbdots;
    __device__ void operator()(int zh, int, int row, int col, float v) const {
        atomicAdd(pbdots + (long)zh * 262144 + (long)row * 512 + col, v);
    }
};
struct EpiDotsPart {  // split-K, no atomics, CHUNKED (16-B stores): zk==0 folds
                      // into pbd via float4 RMW (unique owner per element);
                      // zk>=1 streams float4 to private partial buffers.
    static constexpr bool chunked = true;
    static constexpr bool kv = false;
    static constexpr int vbase = 0;
    static constexpr int ylim = -1;
    float* pbd; float* parts;
    __device__ void chunk(int zh, int zk, int row, int col, float4 a, float4 b) const {
        long idx = (long)zh * 262144 + (long)row * 512 + col;
        if (zk == 0) {
            float4* p = (float4*)(pbd + idx);
            float4 p0 = p[0], p1 = p[1];
            p0.x += a.x; p0.y += a.y; p0.z += a.z; p0.w += a.w;
            p1.x += b.x; p1.y += b.y; p1.z += b.z; p1.w += b.w;
            p[0] = p0; p[1] = p1;
        } else {
            float4* p = (float4*)(parts + (long)(zk - 1) * 2097152 + idx);
            p[0] = a; p[1] = b;
        }
    }
};
struct EpiPV {  // rows=i, cols=(r,d), z=h -> O2[(r*512+i)][(h*64+d)] bf16
    static constexpr bool chunked = true;
    static constexpr bool kv = false;
    static constexpr int vbase = 0;
    static constexpr int ylim = -1;
    u16* O2;
    __device__ void chunk(int zh, int, int row, int col, float4 a, float4 b) const {
        int r = col >> 6, d = col & 63;
        *(uint4*)(O2 + ((long)r * 512 + row) * 512 + zh * 64 + d) = pack8(a, b);
    }
};
struct EpiOut {  // final: out[row*128+col] = v + bo[col], fp32
    static constexpr bool chunked = true;
    static constexpr bool kv = false;
    static constexpr int vbase = 0;
    static constexpr int ylim = -1;
    float* out; const float* bo;
    __device__ void chunk(int, int, int row, int col, float4 a, float4 b) const {
        const float4* bp = (const float4*)(bo + col);
        float4 b0 = bp[0], b1 = bp[1];
        a.x += b0.x; a.y += b0.y; a.z += b0.z; a.w += b0.w;
        b.x += b1.x; b.y += b1.y; b.z += b1.z; b.w += b1.w;
        float4* o = (float4*)(out + (long)row * 128 + col);
        o[0] = a; o[1] = b;
    }
};

// ---------------------------------------------------------------------------
// 32x32 fp32->bf16 transpose tile (device helper for prep_kernel)
// ---------------------------------------------------------------------------
__device__ inline void trans_dev(const float* __restrict__ src, u16* __restrict__ dst,
                                 int R, int C, int bx, int by, int tid)
{
    __shared__ u16 t[32][33];
    int c0 = bx * 32, r0 = by * 32;
    int tx = tid & 31, ty = tid >> 5;   // 32 x 8
#pragma unroll
    for (int i = 0; i < 32; i += 8) t[ty + i][tx] = f2bf(src[(long)(r0 + ty + i) * C + c0 + tx]);
    __syncthreads();
#pragma unroll
    for (int i = 0; i < 32; i += 8) dst[(long)(c0 + ty + i) * R + r0 + tx] = t[tx][ty + i];
}

// ---------------------------------------------------------------------------
// Mega-prep: f2bf(x) + 5 weight transposes + pbprep in ONE dispatch.
// Block routing: [0,2048) f2bf; then 64 Wq, 128 Wkv, 16 Wsk, 16 Wsq, 64 Wo
// transpose tiles; final block = pbprep. Total 2337 blocks.
// ---------------------------------------------------------------------------
__global__ __launch_bounds__(256) void prep_kernel(
    const float* __restrict__ x, u16* __restrict__ xbf,
    const float* __restrict__ Wq, u16* __restrict__ WqT,
    const float* __restrict__ Wkv, u16* __restrict__ WkvT,
    const float* __restrict__ Wsk, u16* __restrict__ WskT,
    const float* __restrict__ Wsq, u16* __restrict__ WsqT,
    const float* __restrict__ Wo, u16* __restrict__ WoT,
    const float* __restrict__ g, const float* __restrict__ b,
    const float* __restrict__ Wp, float* __restrict__ Wg, float* __restrict__ SB)
{
    int gb = blockIdx.x, tid = threadIdx.x;
    if (gb < 2048) { long i = ((long)gb * 256 + tid) * 8; ld8(xbf + i, x + i); return; }
    gb -= 2048;
    if (gb < 64)  { trans_dev(Wq,  WqT,  128, 512,  gb & 15, gb >> 4, tid); return; }
    gb -= 64;
    if (gb < 128) { trans_dev(Wkv, WkvT, 128, 1024, gb & 31, gb >> 5, tid); return; }
    gb -= 128;
    if (gb < 16)  { trans_dev(Wsk, WskT, 128, 128,  gb & 3,  gb >> 2, tid); return; }
    gb -= 16;
    if (gb < 16)  { trans_dev(Wsq, WsqT, 128, 128,  gb & 3,  gb >> 2, tid); return; }
    gb -= 16;
    if (gb < 64)  { trans_dev(Wo,  WoT,  512, 128,  gb & 3,  gb >> 2, tid); return; }
    // final block: pbprep — Wg[c*8+h] = g[c]*Wp[c*8+h]; SB = {g.Wp, b.Wp}
    for (int t = tid; t < 1024; t += 256) Wg[t] = g[t >> 3] * Wp[t];
    if (tid < 16) {
        int h = tid & 7;
        const float* src = (tid < 8) ? g : b;
        float s = 0.f;
        for (int c = 0; c < 128; c++) s += src[c] * Wp[c * 8 + h];
        SB[tid] = s;
    }
}

// ---------------------------------------------------------------------------
// Tie-row weights: wave per (i,h); lane = r. logit = <sq[i,h,:],sk[r,i,h,:]>/4
// ---------------------------------------------------------------------------
__global__ __launch_bounds__(256) void rowweight_kernel(const u16* __restrict__ sk, const u16* __restrict__ sq,
                                                        float* __restrict__ w)
{
    int wid = blockIdx.x * 4 + (threadIdx.x >> 6);  // 0..4095 = i*8+h
    int lane = threadIdx.x & 63;                    // r
    int i = wid >> 3, h = wid & 7;
    const u16* sqp = sq + i * 128 + h * 16;
    const u16* skp = sk + ((long)lane * 512 + i) * 128 + h * 16;
    float dot = 0.f;
#pragma unroll
    for (int c = 0; c < 16; c++) dot += bf2f(sqp[c]) * bf2f(skp[c]);
    float logit = dot * 0.25f;
    float m = logit;
#pragma unroll
    for (int o = 32; o > 0; o >>= 1) m = fmaxf(m, __shfl_xor(m, o));
    float e = __expf(logit - m);
    float ssum = e;
#pragma unroll
    for (int o = 32; o > 0; o >>= 1) ssum += __shfl_xor(ssum, o);
    w[(long)wid * 64 + lane] = e / ssum;
}

// ---------------------------------------------------------------------------
// pair_bias LN + Linear(128->8), LDS-staged, coalesced. 64 rows per block.
// acc_h = rstd*(dot(v,Wg_h) - mu*S_h) + B_h
// ---------------------------------------------------------------------------
__global__ __launch_bounds__(256) void pb_kernel(const float* __restrict__ pair, const float* __restrict__ Wg,
                                                 const float* __restrict__ SB, float* __restrict__ pb)
{
    __shared__ __align__(16) float Ls[64 * 132];
    __shared__ float sWg[1024];
    __shared__ float sSB[16];
    int tid = threadIdx.x;
    for (int t = tid; t < 1024; t += 256) sWg[t] = Wg[t];
    if (tid < 16) sSB[tid] = SB[tid];
    long base = (long)blockIdx.x * 8192;  // 64 rows * 128
    const float4* src = (const float4*)(pair + base);
#pragma unroll
    for (int k = 0; k < 8; k++) {
        int e = tid + k * 256;               // float4 index in tile, 0..2047
        float4 v = src[e];
        int r = e >> 5, c = (e & 31) << 2;
        *(float4*)(&Ls[r * 132 + c]) = v;
    }
    __syncthreads();
    int r = tid >> 2, sub = tid & 3;
    const float* row = &Ls[r * 132];
    float sum = 0.f, sqs = 0.f;
#pragma unroll
    for (int k = 0; k < 8; k++) {
        float4 v = *(const float4*)(&row[sub * 32 + k * 4]);
        sum += v.x + v.y + v.z + v.w;
        sqs += v.x * v.x + v.y * v.y + v.z * v.z + v.w * v.w;
    }
    sum += __shfl_xor(sum, 1); sqs += __shfl_xor(sqs, 1);
    sum += __shfl_xor(sum, 2); sqs += __shfl_xor(sqs, 2);
    float mu = sum * (1.f / 128.f);
    float var = sqs * (1.f / 128.f) - mu * mu;
    float rstd = rsqrtf(var + 1e-5f);
    int h0 = sub * 2;
    float a0 = 0.f, a1 = 0.f;
#pragma unroll
    for (int k = 0; k < 32; k++) {
        float4 v = *(const float4*)(&row[k * 4]);
        int c = k * 4;
        a0 += v.x * sWg[c * 8 + h0]     + v.y * sWg[(c + 1) * 8 + h0]
            + v.z * sWg[(c + 2) * 8 + h0] + v.w * sWg[(c + 3) * 8 + h0];
        a1 += v.x * sWg[c * 8 + h0 + 1]     + v.y * sWg[(c + 1) * 8 + h0 + 1]
            + v.z * sWg[(c + 2) * 8 + h0 + 1] + v.w * sWg[(c + 3) * 8 + h0 + 1];
    }
    long idx = (long)blockIdx.x * 64 + r;
    pb[(long)h0 * 262144 + idx]       = rstd * (a0 - mu * sSB[h0])     + sSB[8 + h0];
    pb[(long)(h0 + 1) * 262144 + idx] = rstd * (a1 - mu * sSB[h0 + 1]) + sSB[8 + h0 + 1];
}

// ---------------------------------------------------------------------------
// Row softmax over 512 cols; wave per row (h*512+i). fp32 in, bf16 out.
// np extra split-K partials are summed in before the softmax.
// ---------------------------------------------------------------------------
__global__ __launch_bounds__(256) void softmax_kernel(const float* __restrict__ dots,
                                                      const float* __restrict__ parts, int np,
                                                      u16* __restrict__ attn)
{
    int row = blockIdx.x * 4 + (threadIdx.x >> 6);
    int lane = threadIdx.x & 63;
    long base = (long)row * 512;
    const float* dp = dots + base;
    float v[8];
#pragma unroll
    for (int k = 0; k < 8; k++) v[k] = dp[k * 64 + lane];
    for (int t = 0; t < np; t++) {
        const float* pp = parts + (long)t * 2097152 + base;
#pragma unroll
        for (int k = 0; k < 8; k++) v[k] += pp[k * 64 + lane];
    }
    float m = v[0];
#pragma unroll
    for (int k = 1; k < 8; k++) m = fmaxf(m, v[k]);
#pragma unroll
    for (int o = 32; o > 0; o >>= 1) m = fmaxf(m, __shfl_xor(m, o));
    float s = 0.f;
#pragma unroll
    for (int k = 0; k < 8; k++) { v[k] = __expf(v[k] - m); s += v[k]; }
#pragma unroll
    for (int o = 32; o > 0; o >>= 1) s += __shfl_xor(s, o);
    float inv = 1.f / s;
    u16* ap = attn + (long)row * 512;
#pragma unroll
    for (int k = 0; k < 8; k++) ap[k * 64 + lane] = f2bf(v[k] * inv);
}

// ---------------------------------------------------------------------------
extern "C" void kernel_launch(void* const* d_in, const int* in_sizes, int n_in,
                              void* d_out, int out_size, void* d_ws, size_t ws_size,
                              hipStream_t stream)
{
    const float* x    = (const float*)d_in[0];
    const float* pair = (const float*)d_in[1];
    const float* Wq   = (const float*)d_in[2];
    const float* Wkv  = (const float*)d_in[3];
    const float* Wo   = (const float*)d_in[4];
    const float* bo   = (const float*)d_in[5];
    const float* lng  = (const float*)d_in[6];
    const float* lnb  = (const float*)d_in[7];
    const float* Wp   = (const float*)d_in[8];
    const float* Wsq  = (const float*)d_in[9];
    const float* bsq  = (const float*)d_in[10];
    const float* Wsk  = (const float*)d_in[11];
    const float* bsk  = (const float*)d_in[12];
    float* out = (float*)d_out;

    char* ws = (char*)d_ws;
    size_t off = 0;
    auto alloc = [&](size_t bytes) -> char* {
        char* p = ws + off; off += (bytes + 255) & ~(size_t)255; return p;
    };
    u16* WqT  = (u16*)alloc(512 * 128 * 2);     // WkvT MUST follow contiguously:
    u16* WkvT = (u16*)alloc(1024 * 128 * 2);    //   fused QKV uses B=WqT+col0*128
    u16* WskT = (u16*)alloc(128 * 128 * 2);     // WsqT MUST follow (sBz=16384)
    u16* WsqT = (u16*)alloc(128 * 128 * 2);
    u16* WoT  = (u16*)alloc(128 * 512 * 2);
    u16* xbf  = (u16*)alloc((size_t)32768 * 128 * 2);
    u16* sk   = (u16*)alloc((size_t)32768 * 128 * 2);   // later reused as attn
    u16* sq   = (u16*)alloc(512 * 128 * 2);
    float* w  = (float*)alloc((size_t)4096 * 64 * 4);
    float* Wg = (float*)alloc(1024 * 4);
    float* SB = (float*)alloc(16 * 4);
    u16* bufA = (u16*)alloc((size_t)8 * 512 * 4096 * 2);  // Qw
    u16* bufB = (u16*)alloc((size_t)8 * 512 * 4096 * 2);  // Kp, then O2
    u16* Vt   = (u16*)alloc((size_t)8 * 4096 * 512 * 2);
    float* pbd = (float*)alloc((size_t)8 * 512 * 512 * 4);  // pb, then dots (+partial 0)
    // allocated LAST so the atomic fallback still fits if ws is small:
    float* parts = (float*)alloc((size_t)3 * 2097152 * 4);  // split-K partials 1..3
    const bool useParts = (off <= ws_size);
    u16* attn = sk;  // alias: sk dead after rowweight_kernel

    dim3 blk(256);

    // 1) mega-prep: f2bf + 5 weight transposes + pbprep
    prep_kernel<<<dim3(2337), blk, 0, stream>>>(x, xbf, Wq, WqT, Wkv, WkvT,
                                                Wsk, WskT, Wsq, WsqT, Wo, WoT,
                                                lng, lnb, Wp, Wg, SB);

    // 2) sk + sq projections in ONE dispatch (z=0: sk, z=1: sq via sBz offset)
    gemm_nt<64, 128, EpiSkSq><<<dim3(1, 512, 2), blk, 0, stream>>>(
        xbf, WskT, 0, 16384, 128, 128, 128, 0, EpiSkSq{sk, sq, bsk, bsq});
    rowweight_kernel<<<dim3(1024), blk, 0, stream>>>(sk, sq, w);

    // 3) pair-bias LN + projection -> pbd (fp32). BEFORE QKV: the 134 MB pair
    //    stream runs first, so Qw/Kp/Vt are L3-warm when dots/PV read them.
    pb_kernel<<<dim3(4096), blk, 0, stream>>>(pair, Wg, SB, pbd);

    // 4) fused Q+KV projection (N=1536, WqT||WkvT contiguous), BM=64 ->
    //    4 blocks/CU: Qw (w-scaled), Kp, Vt DIRECT (transposed epilogue).
    gemm_nt<64, 128, EpiQKV><<<dim3(12, 512, 1), blk, 0, stream>>>(
        xbf, WqT, 0, 0, 128, 128, 128, 0, EpiQKV{bufA, bufB, Vt, w});

    // 5) dots[h] = Qw[h] @ Kp[h]^T + pb.  BM=64: grid 1024 = 4 blocks/CU
    //    (was 512 = 2/CU; r0 PMC showed Occupancy 31%, latency-bound).
    if (useParts) {
        // split-K=4, NO atomics, chunked 16-B epilogue: zk=0 folds into pbd
        // (unique-owner float4 RMW), zk=1..3 stream float4 partials.
        gemm_nt<64, 128, EpiDotsPart><<<dim3(4, 8, 32), blk, 0, stream>>>(
            bufA, bufB, 2097152, 2097152, 4096, 4096, 1024, 2, EpiDotsPart{pbd, parts});
        softmax_kernel<<<dim3(1024), blk, 0, stream>>>(pbd, parts, 3, attn);
    } else {
        // fallback (workspace too small): proven atomic split-K=8 path
        gemm_nt<128, 128, EpiDotsAtomic><<<dim3(4, 4, 64), blk, 0, stream>>>(
            bufA, bufB, 2097152, 2097152, 4096, 4096, 512, 3, EpiDotsAtomic{pbd});
        softmax_kernel<<<dim3(1024), blk, 0, stream>>>(pbd, pbd, 0, attn);
    }

    // 6) O[h] = attn[h] @ Vt[h]^T -> O2 (bufB, Kp dead). BM=64: 2048 blocks,
    //    36.9KB LDS -> 4 blocks/CU (was 3/CU at 48KB, grid-capped).
    gemm_nt<64, 128, EpiPV><<<dim3(32, 8, 8), blk, 0, stream>>>(
        attn, Vt, 262144, 2097152, 512, 512, 512, 0, EpiPV{bufB});

    // 7) final projection: O2 @ Wo + bo -> out (fp32)
    gemm_nt<64, 128, EpiOut><<<dim3(1, 512, 1), blk, 0, stream>>>(
        bufB, WoT, 0, 0, 512, 512, 512, 0, EpiOut{out, bo});
}

// Round 9
// 365.913 us; speedup vs baseline: 1.0229x; 1.0229x over previous
//
#include <hip/hip_runtime.h>
#include <hip/hip_bf16.h>

typedef unsigned short u16;
typedef unsigned int u32;
typedef __attribute__((ext_vector_type(8))) short short8;
typedef __attribute__((ext_vector_type(4))) float floatx4;

__device__ inline float bf2f(u16 u) { union { u32 i; float f; } v; v.i = ((u32)u) << 16; return v.f; }
__device__ inline u16 f2bf(float f) {
    union { float f; u32 i; } v; v.f = f;
    u32 lsb = (v.i >> 16) & 1u;
    v.i += 0x7fffu + lsb;              // round-to-nearest-even
    return (u16)(v.i >> 16);
}

__device__ inline uint4 pack8(float4 a, float4 b) {
    uint4 q;
    q.x = (u32)f2bf(a.x) | ((u32)f2bf(a.y) << 16);
    q.y = (u32)f2bf(a.z) | ((u32)f2bf(a.w) << 16);
    q.z = (u32)f2bf(b.x) | ((u32)f2bf(b.y) << 16);
    q.w = (u32)f2bf(b.z) | ((u32)f2bf(b.w) << 16);
    return q;
}

__device__ inline void ld8(u16* dst, const float* src) {
    const float4 a = *(const float4*)src;
    const float4 b = *(const float4*)(src + 4);
    *(uint4*)dst = pack8(a, b);
}

// async 16B global->LDS DMA; ldst must be wave-uniform (dest = ldst + lane*16)
__device__ inline void async16(u16* ldst, const u16* gsrc) {
    __builtin_amdgcn_global_load_lds((const __attribute__((address_space(1))) u32*)gsrc,
                                     (__attribute__((address_space(3))) u32*)ldst, 16, 0, 0);
}

// counted vmcnt wait (never drain to 0 in the main loop - T4); "memory" clobber
// pins all memory ops (ds_read/global_load_lds) on the correct side.
template <int N> __device__ inline void waitvm() {
    static_assert(N == 0 || N == 2 || N == 3 || N == 4 || N == 6 || N == 8, "unsupported vmcnt");
    if constexpr (N == 0) asm volatile("s_waitcnt vmcnt(0)" ::: "memory");
    if constexpr (N == 2) asm volatile("s_waitcnt vmcnt(2)" ::: "memory");
    if constexpr (N == 3) asm volatile("s_waitcnt vmcnt(3)" ::: "memory");
    if constexpr (N == 4) asm volatile("s_waitcnt vmcnt(4)" ::: "memory");
    if constexpr (N == 6) asm volatile("s_waitcnt vmcnt(6)" ::: "memory");
    if constexpr (N == 8) asm volatile("s_waitcnt vmcnt(8)" ::: "memory");
}
__device__ inline void barrier_raw() {
    asm volatile("s_barrier" ::: "memory");
    __builtin_amdgcn_sched_barrier(0);      // pin schedule at the phase boundary
}
__device__ inline void waitlgkm0() {
    // rule #18: inline lgkmcnt wait must be followed by sched_barrier(0) or
    // hipcc may hoist register-only MFMAs above it (they ignore "memory").
    asm volatile("s_waitcnt lgkmcnt(0)" ::: "memory");
    __builtin_amdgcn_sched_barrier(0);
}

// ---------------------------------------------------------------------------
// NT GEMM: C[MxN] = A[MxK] @ B[NxK]^T, bf16 in / fp32 MFMA accum.
// 3-slot LDS ring, 2-ahead prefetch, counted vmcnt (T3/T4) — verified r5-r7.
//   prologue: stage(0), stage(1)
//   iter i:   s_waitcnt vmcnt(PW); s_barrier; stage(slot of i+2);
//             ds_read frags; lgkmcnt(0); MFMA on slot of i
//   tail:     vmcnt(PW) / vmcnt(0) peeled iters.
// Epi::xswz (T1, m204): bijective XCD-chunked block remap. HW round-robins
// consecutive linear block ids across the 8 XCDs; the remap gives each XCD a
// CONTIGUOUS wgid run, so blocks sharing an operand panel (same z / same-y
// runs) land on ONE XCD and the panel stays L2-resident. All swizzled grids
// have n%8==0 (dots 512, PV 1024, QKV 3072) so wg=(o%8)*(n/8)+o/8 is exact.
// Epilogue: chunked epis stage the fp32 C-tile through LDS in 64-row passes,
// emit 16-B coalesced chunks. Epi::kv: tiles with col0>=vbase stage TRANSPOSED
// (cs[col*68+row]) and emit j-contiguous chunks into Vt directly.
// Epi::ylim>=0: blocks with zh!=0 && by>=ylim exit early (sq fold).
// ---------------------------------------------------------------------------
template <int BM, int BN, class Epi>
__global__ __launch_bounds__(256) void gemm_nt(const u16* __restrict__ A, const u16* __restrict__ B,
                                               long sAz, long sBz, int lda, int ldb, int K, int zlog, Epi epi)
{
    constexpr int AELE = BM * 32, BELE = BN * 32;   // elements per matrix per slot
    constexpr int SLOT = AELE + BELE;
    constexpr int IA = BM / 64, IB = BN / 64;       // DMA issues per wave per stage
    constexpr int PW = IA + IB;                      // vmcnt ops per wave per stage
    constexpr bool STAGE = Epi::chunked;
    static_assert(!STAGE || BN == 128, "chunked epilogue assumes BN=128");
    constexpr int LDC = BN + 4;                      // fp32 staging stride
    constexpr size_t RB = sizeof(u16) * 3 * (size_t)SLOT;            // ring bytes
    constexpr size_t EBR = STAGE ? sizeof(float) * 64 * (size_t)LDC : 0;
    constexpr size_t EBV = (STAGE && Epi::kv) ? sizeof(float) * 128 * 68 : 0;
    constexpr size_t EB = EBR > EBV ? EBR : EBV;
    constexpr size_t LB = RB > EB ? RB : EB;
    __shared__ __align__(16) char smem[LB];
    u16* lds = (u16*)smem;
    const int tid  = threadIdx.x;
    const int lane = tid & 63;
    const int wave = tid >> 6;

    int bx = blockIdx.x, by = blockIdx.y, bz = blockIdx.z;
    if constexpr (Epi::xswz) {                       // T1: XCD-chunked remap
        int gx = gridDim.x, gy = gridDim.y;
        int n = gx * gy * (int)gridDim.z;            // launch guarantees n%8==0
        int o = (bz * gy + by) * gx + bx;
        int wg = (o & 7) * (n >> 3) + (o >> 3);
        bx = wg % gx; int t = wg / gx; by = t % gy; bz = t / gy;
    }
    const int zh = bz >> zlog;
    const int zk = bz & ((1 << zlog) - 1);
    if constexpr (Epi::ylim >= 0) {                  // sq fold: skip unused blocks
        if (zh != 0 && by >= Epi::ylim) return;
    }
    const long row0 = (long)by * BM;
    const long col0 = (long)bx * BN;
    const u16* Ab = A + (long)zh * sAz + row0 * lda + (long)zk * K;
    const u16* Bb = B + (long)zh * sBz + col0 * ldb + (long)zk * K;
    constexpr int WM = BM / 2, WN = BN / 2, TM = WM / 16, TN = WN / 16;
    const int wm = (wave >> 1) * WM;
    const int wn = (wave & 1) * WN;
    const int l15 = lane & 15;
    const int quad = lane >> 4;
    const int swz = (l15 >> 1) & 3;   // (row>>1)&3 for row = 16*t + l15

    floatx4 acc[TM][TN];
#pragma unroll
    for (int i = 0; i < TM; i++)
#pragma unroll
        for (int j = 0; j < TN; j++) acc[i][j] = (floatx4){0.f, 0.f, 0.f, 0.f};

    auto stage = [&](int slot, int ki) {
        const int k0 = ki << 5;
        u16* base = lds + slot * SLOT;
#pragma unroll
        for (int i2 = 0; i2 < IA; i2++) {
            int s = wave * (IA * 64) + i2 * 64 + lane;       // chunk slot
            int r = s >> 2, c = (s & 3) ^ ((r >> 1) & 3);
            async16(base + (wave * (IA * 64) + i2 * 64) * 8, Ab + (long)r * lda + k0 + c * 8);
        }
        u16* bbase = base + AELE;
#pragma unroll
        for (int i2 = 0; i2 < IB; i2++) {
            int s = wave * (IB * 64) + i2 * 64 + lane;
            int r = s >> 2, c = (s & 3) ^ ((r >> 1) & 3);
            async16(bbase + (wave * (IB * 64) + i2 * 64) * 8, Bb + (long)r * ldb + k0 + c * 8);
        }
    };

    auto compute = [&](int slot) {
        const u16* As = lds + slot * SLOT;
        const u16* Bs = As + AELE;
        short8 af[TM], bfr[TN];
#pragma unroll
        for (int t = 0; t < TM; t++)
            af[t] = *(const short8*)(As + (wm + t * 16 + l15) * 32 + (quad ^ swz) * 8);
#pragma unroll
        for (int t = 0; t < TN; t++)
            bfr[t] = *(const short8*)(Bs + (wn + t * 16 + l15) * 32 + (quad ^ swz) * 8);
        waitlgkm0();                     // frag reads retired before next barrier
#pragma unroll
        for (int i = 0; i < TM; i++)
#pragma unroll
            for (int j = 0; j < TN; j++)
                acc[i][j] = __builtin_amdgcn_mfma_f32_16x16x32_bf16(af[i], bfr[j], acc[i][j], 0, 0, 0);
    };

    const int nIter = K >> 5;                        // K >= 128 -> nIter >= 4
    stage(0, 0);
    stage(1, 1);
    int s0 = 0, s1 = 1, s2 = 2;                      // slots of tiles i, i+1, i+2
    for (int i = 0; i + 2 < nIter; i++) {
        waitvm<PW>();
        barrier_raw();
        stage(s2, i + 2);                            // overwrites slot of tile i-1
        compute(s0);
        int t = s0; s0 = s1; s1 = s2; s2 = t;
    }
    waitvm<PW>(); barrier_raw(); compute(s0);
    waitvm<0>();  barrier_raw(); compute(s1);

    if constexpr (STAGE) {
        float* cs = (float*)smem;
        constexpr int NP = BM / 64;                  // 64-row passes
        bool vtile = false;
        if constexpr (Epi::kv) vtile = (col0 >= Epi::vbase);
#pragma unroll
        for (int p = 0; p < NP; p++) {
            __syncthreads();                         // prev reads done before overwrite
            if (!vtile) {
                if ((wm >> 6) == p) {
                    const int lr0 = wm & 63;
#pragma unroll
                    for (int i = 0; i < TM; i++)
#pragma unroll
                        for (int j = 0; j < TN; j++)
#pragma unroll
                            for (int r = 0; r < 4; r++)
                                cs[(lr0 + i * 16 + quad * 4 + r) * LDC + wn + j * 16 + l15] = acc[i][j][r];
                }
                __syncthreads();
                constexpr int CPT = (64 * BN) / (256 * 8);   // 16-B chunks per thread
#pragma unroll
                for (int k = 0; k < CPT; k++) {
                    int g = k * 256 + tid;
                    int row = g >> 4, c8 = (g & 15) * 8;
                    const float* pp = cs + row * LDC + c8;
                    float4 a = *(const float4*)pp;
                    float4 b = *(const float4*)(pp + 4);
                    epi.chunk(zh, zk, (int)row0 + p * 64 + row, (int)col0 + c8, a, b);
                }
            }
            if constexpr (Epi::kv) {
                if (vtile) {
                    // transposed staging: cs[col*68 + row], float4 per lane
                    if ((wm >> 6) == p) {
                        const int lr0 = wm & 63;
#pragma unroll
                        for (int i = 0; i < TM; i++)
#pragma unroll
                            for (int j = 0; j < TN; j++)
                                *(float4*)&cs[(wn + j * 16 + l15) * 68 + lr0 + i * 16 + quad * 4] =
                                    (float4){acc[i][j][0], acc[i][j][1], acc[i][j][2], acc[i][j][3]};
                    }
                    __syncthreads();
#pragma unroll
                    for (int k = 0; k < 4; k++) {    // 128 cols x 8 row-groups
                        int q = k * 256 + tid;
                        int colL = q >> 3, rg = q & 7;
                        const float* pp = cs + colL * 68 + rg * 8;
                        float4 a = *(const float4*)pp;
                        float4 b = *(const float4*)(pp + 4);
                        epi.vchunk(zh, (int)row0 + p * 64 + rg * 8, (int)col0 + colL, a, b);
                    }
                }
            }
        }
    } else {
#pragma unroll
        for (int i = 0; i < TM; i++)
#pragma unroll
            for (int j = 0; j < TN; j++)
#pragma unroll
                for (int r = 0; r < 4; r++) {
                    int row = (int)row0 + wm + i * 16 + quad * 4 + r;
                    int col = (int)col0 + wn + j * 16 + l15;
                    epi(zh, zk, row, col, acc[i][j][r]);
                }
    }
}

// --- epilogues -------------------------------------------------------------
struct EpiSkSq {  // zh=0: sk = x@Wsk + bsk (rows 0..32767); zh=1: sq (rows 0..511)
    static constexpr bool chunked = true;
    static constexpr bool kv = false;
    static constexpr bool xswz = false;
    static constexpr int vbase = 0;
    static constexpr int ylim = 8;     // zh=1 uses only blocks y<8
    u16* sk; u16* sq; const float* bsk; const float* bsq;
    __device__ void chunk(int zh, int, int row, int col, float4 a, float4 b) const {
        const float* bias = zh ? bsq : bsk;
        u16* C = zh ? sq : sk;
        const float4* bp = (const float4*)(bias + col);
        float4 b0 = bp[0], b1 = bp[1];
        a.x += b0.x; a.y += b0.y; a.z += b0.z; a.w += b0.w;
        b.x += b1.x; b.y += b1.y; b.z += b1.z; b.w += b1.w;
        *(uint4*)(C + (long)row * 128 + col) = pack8(a, b);
    }
};
struct EpiQKV {  // fused Q+KV projection. cols: [0,512) Qw (w-scaled);
                 // [512,1024) Kp; [1024,1536) Vt via transposed vchunk.
    static constexpr bool chunked = true;
    static constexpr bool kv = true;
    static constexpr bool xswz = true;
    static constexpr int vbase = 1024;
    static constexpr int ylim = -1;
    u16* Qw; u16* Kp; u16* Vt; const float* w;
    __device__ void chunk(int, int, int row, int col, float4 a, float4 b) const {
        int r = row >> 9, i = row & 511;
        if (col < 512) {
            int h = col >> 6, d = col & 63;
            float s = w[((long)(i * 8 + h)) * 64 + r] * 0.125f;
            a.x *= s; a.y *= s; a.z *= s; a.w *= s;
            b.x *= s; b.y *= s; b.z *= s; b.w *= s;
            *(uint4*)(Qw + (long)h * 2097152 + (long)i * 4096 + r * 64 + d) = pack8(a, b);
        } else {
            int c = col - 512, h = c >> 6, d = c & 63;
            *(uint4*)(Kp + (long)h * 2097152 + (long)i * 4096 + r * 64 + d) = pack8(a, b);
        }
    }
    __device__ void vchunk(int, int row8, int col, float4 a, float4 b) const {
        // 8 packed values = global rows row8..row8+7 (same r, consecutive j)
        int r = row8 >> 9, j0 = row8 & 511;
        int c = col - vbase, h = c >> 6, d = c & 63;
        *(uint4*)(Vt + (long)h * 2097152 + ((long)r * 64 + d) * 512 + j0) = pack8(a, b);
    }
};
struct EpiDotsAtomic {  // fallback: dots[zh][row][col] += v (pb resident), fp32
    static constexpr bool chunked = false;
    static constexpr bool kv = false;
    static constexpr bool xswz = false;
    static constexpr int vbase = 0;
    static constexpr int ylim = -1;
    float* pbdots;
    __device__ void operator()(int zh, int, int row, int col, float v) const {
        atomicAdd(pbdots + (long)zh * 262144 + (long)row * 512 + col, v);
    }
};
struct EpiDotsPart {  // split-K, no atomics, CHUNKED (16-B stores): zk==0 folds
                      // into pbd via float4 RMW (unique owner per element);
                      // zk>=1 streams float4 to private partial buffers.
    static constexpr bool chunked = true;
    static constexpr bool kv = false;
    static constexpr bool xswz = true;
    static constexpr int vbase = 0;
    static constexpr int ylim = -1;
    float* pbd; float* parts;
    __device__ void chunk(int zh, int zk, int row, int col, float4 a, float4 b) const {
        long idx = (long)zh * 262144 + (long)row * 512 + col;
        if (zk == 0) {
            float4* p = (float4*)(pbd + idx);
            float4 p0 = p[0], p1 = p[1];
            p0.x += a.x; p0.y += a.y; p0.z += a.z; p0.w += a.w;
            p1.x += b.x; p1.y += b.y; p1.z += b.z; p1.w += b.w;
            p[0] = p0; p[1] = p1;
        } else {
            float4* p = (float4*)(parts + (long)(zk - 1) * 2097152 + idx);
            p[0] = a; p[1] = b;
        }
    }
};
struct EpiPV {  // rows=i, cols=(r,d), z=h -> O2[(r*512+i)][(h*64+d)] bf16
    static constexpr bool chunked = true;
    static constexpr bool kv = false;
    static constexpr bool xswz = true;
    static constexpr int vbase = 0;
    static constexpr int ylim = -1;
    u16* O2;
    __device__ void chunk(int zh, int, int row, int col, float4 a, float4 b) const {
        int r = col >> 6, d = col & 63;
        *(uint4*)(O2 + ((long)r * 512 + row) * 512 + zh * 64 + d) = pack8(a, b);
    }
};
struct EpiOut {  // final: out[row*128+col] = v + bo[col], fp32
    static constexpr bool chunked = true;
    static constexpr bool kv = false;
    static constexpr bool xswz = false;
    static constexpr int vbase = 0;
    static constexpr int ylim = -1;
    float* out; const float* bo;
    __device__ void chunk(int, int, int row, int col, float4 a, float4 b) const {
        const float4* bp = (const float4*)(bo + col);
        float4 b0 = bp[0], b1 = bp[1];
        a.x += b0.x; a.y += b0.y; a.z += b0.z; a.w += b0.w;
        b.x += b1.x; b.y += b1.y; b.z += b1.z; b.w += b1.w;
        float4* o = (float4*)(out + (long)row * 128 + col);
        o[0] = a; o[1] = b;
    }
};

// ---------------------------------------------------------------------------
// 32x32 fp32->bf16 transpose tile (device helper for prep_kernel)
// ---------------------------------------------------------------------------
__device__ inline void trans_dev(const float* __restrict__ src, u16* __restrict__ dst,
                                 int R, int C, int bx, int by, int tid)
{
    __shared__ u16 t[32][33];
    int c0 = bx * 32, r0 = by * 32;
    int tx = tid & 31, ty = tid >> 5;   // 32 x 8
#pragma unroll
    for (int i = 0; i < 32; i += 8) t[ty + i][tx] = f2bf(src[(long)(r0 + ty + i) * C + c0 + tx]);
    __syncthreads();
#pragma unroll
    for (int i = 0; i < 32; i += 8) dst[(long)(c0 + ty + i) * R + r0 + tx] = t[tx][ty + i];
}

// ---------------------------------------------------------------------------
// Mega-prep: f2bf(x) + 5 weight transposes + pbprep in ONE dispatch.
// Block routing: [0,2048) f2bf; then 64 Wq, 128 Wkv, 16 Wsk, 16 Wsq, 64 Wo
// transpose tiles; final block = pbprep. Total 2337 blocks.
// ---------------------------------------------------------------------------
__global__ __launch_bounds__(256) void prep_kernel(
    const float* __restrict__ x, u16* __restrict__ xbf,
    const float* __restrict__ Wq, u16* __restrict__ WqT,
    const float* __restrict__ Wkv, u16* __restrict__ WkvT,
    const float* __restrict__ Wsk, u16* __restrict__ WskT,
    const float* __restrict__ Wsq, u16* __restrict__ WsqT,
    const float* __restrict__ Wo, u16* __restrict__ WoT,
    const float* __restrict__ g, const float* __restrict__ b,
    const float* __restrict__ Wp, float* __restrict__ Wg, float* __restrict__ SB)
{
    int gb = blockIdx.x, tid = threadIdx.x;
    if (gb < 2048) { long i = ((long)gb * 256 + tid) * 8; ld8(xbf + i, x + i); return; }
    gb -= 2048;
    if (gb < 64)  { trans_dev(Wq,  WqT,  128, 512,  gb & 15, gb >> 4, tid); return; }
    gb -= 64;
    if (gb < 128) { trans_dev(Wkv, WkvT, 128, 1024, gb & 31, gb >> 5, tid); return; }
    gb -= 128;
    if (gb < 16)  { trans_dev(Wsk, WskT, 128, 128,  gb & 3,  gb >> 2, tid); return; }
    gb -= 16;
    if (gb < 16)  { trans_dev(Wsq, WsqT, 128, 128,  gb & 3,  gb >> 2, tid); return; }
    gb -= 16;
    if (gb < 64)  { trans_dev(Wo,  WoT,  512, 128,  gb & 3,  gb >> 2, tid); return; }
    // final block: pbprep — Wg[c*8+h] = g[c]*Wp[c*8+h]; SB = {g.Wp, b.Wp}
    for (int t = tid; t < 1024; t += 256) Wg[t] = g[t >> 3] * Wp[t];
    if (tid < 16) {
        int h = tid & 7;
        const float* src = (tid < 8) ? g : b;
        float s = 0.f;
        for (int c = 0; c < 128; c++) s += src[c] * Wp[c * 8 + h];
        SB[tid] = s;
    }
}

// ---------------------------------------------------------------------------
// Tie-row weights: wave per (i,h); lane = r. logit = <sq[i,h,:],sk[r,i,h,:]>/4
// ---------------------------------------------------------------------------
__global__ __launch_bounds__(256) void rowweight_kernel(const u16* __restrict__ sk, const u16* __restrict__ sq,
                                                        float* __restrict__ w)
{
    int wid = blockIdx.x * 4 + (threadIdx.x >> 6);  // 0..4095 = i*8+h
    int lane = threadIdx.x & 63;                    // r
    int i = wid >> 3, h = wid & 7;
    const u16* sqp = sq + i * 128 + h * 16;
    const u16* skp = sk + ((long)lane * 512 + i) * 128 + h * 16;
    float dot = 0.f;
#pragma unroll
    for (int c = 0; c < 16; c++) dot += bf2f(sqp[c]) * bf2f(skp[c]);
    float logit = dot * 0.25f;
    float m = logit;
#pragma unroll
    for (int o = 32; o > 0; o >>= 1) m = fmaxf(m, __shfl_xor(m, o));
    float e = __expf(logit - m);
    float ssum = e;
#pragma unroll
    for (int o = 32; o > 0; o >>= 1) ssum += __shfl_xor(ssum, o);
    w[(long)wid * 64 + lane] = e / ssum;
}

// ---------------------------------------------------------------------------
// pair_bias LN + Linear(128->8), LDS-staged, coalesced. 64 rows per block.
// acc_h = rstd*(dot(v,Wg_h) - mu*S_h) + B_h
// ---------------------------------------------------------------------------
__global__ __launch_bounds__(256) void pb_kernel(const float* __restrict__ pair, const float* __restrict__ Wg,
                                                 const float* __restrict__ SB, float* __restrict__ pb)
{
    __shared__ __align__(16) float Ls[64 * 132];
    __shared__ float sWg[1024];
    __shared__ float sSB[16];
    int tid = threadIdx.x;
    for (int t = tid; t < 1024; t += 256) sWg[t] = Wg[t];
    if (tid < 16) sSB[tid] = SB[tid];
    long base = (long)blockIdx.x * 8192;  // 64 rows * 128
    const float4* src = (const float4*)(pair + base);
#pragma unroll
    for (int k = 0; k < 8; k++) {
        int e = tid + k * 256;               // float4 index in tile, 0..2047
        float4 v = src[e];
        int r = e >> 5, c = (e & 31) << 2;
        *(float4*)(&Ls[r * 132 + c]) = v;
    }
    __syncthreads();
    int r = tid >> 2, sub = tid & 3;
    const float* row = &Ls[r * 132];
    float sum = 0.f, sqs = 0.f;
#pragma unroll
    for (int k = 0; k < 8; k++) {
        float4 v = *(const float4*)(&row[sub * 32 + k * 4]);
        sum += v.x + v.y + v.z + v.w;
        sqs += v.x * v.x + v.y * v.y + v.z * v.z + v.w * v.w;
    }
    sum += __shfl_xor(sum, 1); sqs += __shfl_xor(sqs, 1);
    sum += __shfl_xor(sum, 2); sqs += __shfl_xor(sqs, 2);
    float mu = sum * (1.f / 128.f);
    float var = sqs * (1.f / 128.f) - mu * mu;
    float rstd = rsqrtf(var + 1e-5f);
    int h0 = sub * 2;
    float a0 = 0.f, a1 = 0.f;
#pragma unroll
    for (int k = 0; k < 32; k++) {
        float4 v = *(const float4*)(&row[k * 4]);
        int c = k * 4;
        a0 += v.x * sWg[c * 8 + h0]     + v.y * sWg[(c + 1) * 8 + h0]
            + v.z * sWg[(c + 2) * 8 + h0] + v.w * sWg[(c + 3) * 8 + h0];
        a1 += v.x * sWg[c * 8 + h0 + 1]     + v.y * sWg[(c + 1) * 8 + h0 + 1]
            + v.z * sWg[(c + 2) * 8 + h0 + 1] + v.w * sWg[(c + 3) * 8 + h0 + 1];
    }
    long idx = (long)blockIdx.x * 64 + r;
    pb[(long)h0 * 262144 + idx]       = rstd * (a0 - mu * sSB[h0])     + sSB[8 + h0];
    pb[(long)(h0 + 1) * 262144 + idx] = rstd * (a1 - mu * sSB[h0 + 1]) + sSB[8 + h0 + 1];
}

// ---------------------------------------------------------------------------
// Row softmax over 512 cols; wave per row (h*512+i). fp32 in, bf16 out.
// np extra split-K partials are summed in before the softmax.
// ---------------------------------------------------------------------------
__global__ __launch_bounds__(256) void softmax_kernel(const float* __restrict__ dots,
                                                      const float* __restrict__ parts, int np,
                                                      u16* __restrict__ attn)
{
    int row = blockIdx.x * 4 + (threadIdx.x >> 6);
    int lane = threadIdx.x & 63;
    long base = (long)row * 512;
    const float* dp = dots + base;
    float v[8];
#pragma unroll
    for (int k = 0; k < 8; k++) v[k] = dp[k * 64 + lane];
    for (int t = 0; t < np; t++) {
        const float* pp = parts + (long)t * 2097152 + base;
#pragma unroll
        for (int k = 0; k < 8; k++) v[k] += pp[k * 64 + lane];
    }
    float m = v[0];
#pragma unroll
    for (int k = 1; k < 8; k++) m = fmaxf(m, v[k]);
#pragma unroll
    for (int o = 32; o > 0; o >>= 1) m = fmaxf(m, __shfl_xor(m, o));
    float s = 0.f;
#pragma unroll
    for (int k = 0; k < 8; k++) { v[k] = __expf(v[k] - m); s += v[k]; }
#pragma unroll
    for (int o = 32; o > 0; o >>= 1) s += __shfl_xor(s, o);
    float inv = 1.f / s;
    u16* ap = attn + (long)row * 512;
#pragma unroll
    for (int k = 0; k < 8; k++) ap[k * 64 + lane] = f2bf(v[k] * inv);
}

// ---------------------------------------------------------------------------
extern "C" void kernel_launch(void* const* d_in, const int* in_sizes, int n_in,
                              void* d_out, int out_size, void* d_ws, size_t ws_size,
                              hipStream_t stream)
{
    const float* x    = (const float*)d_in[0];
    const float* pair = (const float*)d_in[1];
    const float* Wq   = (const float*)d_in[2];
    const float* Wkv  = (const float*)d_in[3];
    const float* Wo   = (const float*)d_in[4];
    const float* bo   = (const float*)d_in[5];
    const float* lng  = (const float*)d_in[6];
    const float* lnb  = (const float*)d_in[7];
    const float* Wp   = (const float*)d_in[8];
    const float* Wsq  = (const float*)d_in[9];
    const float* bsq  = (const float*)d_in[10];
    const float* Wsk  = (const float*)d_in[11];
    const float* bsk  = (const float*)d_in[12];
    float* out = (float*)d_out;

    char* ws = (char*)d_ws;
    size_t off = 0;
    auto alloc = [&](size_t bytes) -> char* {
        char* p = ws + off; off += (bytes + 255) & ~(size_t)255; return p;
    };
    u16* WqT  = (u16*)alloc(512 * 128 * 2);     // WkvT MUST follow contiguously:
    u16* WkvT = (u16*)alloc(1024 * 128 * 2);    //   fused QKV uses B=WqT+col0*128
    u16* WskT = (u16*)alloc(128 * 128 * 2);     // WsqT MUST follow (sBz=16384)
    u16* WsqT = (u16*)alloc(128 * 128 * 2);
    u16* WoT  = (u16*)alloc(128 * 512 * 2);
    u16* xbf  = (u16*)alloc((size_t)32768 * 128 * 2);
    u16* sk   = (u16*)alloc((size_t)32768 * 128 * 2);   // later reused as attn
    u16* sq   = (u16*)alloc(512 * 128 * 2);
    float* w  = (float*)alloc((size_t)4096 * 64 * 4);
    float* Wg = (float*)alloc(1024 * 4);
    float* SB = (float*)alloc(16 * 4);
    u16* bufA = (u16*)alloc((size_t)8 * 512 * 4096 * 2);  // Qw
    u16* bufB = (u16*)alloc((size_t)8 * 512 * 4096 * 2);  // Kp, then O2
    u16* Vt   = (u16*)alloc((size_t)8 * 4096 * 512 * 2);
    float* pbd = (float*)alloc((size_t)8 * 512 * 512 * 4);  // pb, then dots (+partial 0)
    // allocated LAST so the atomic fallback still fits if ws is small:
    float* parts = (float*)alloc((size_t)3 * 2097152 * 4);  // split-K partials 1..3
    const bool useParts = (off <= ws_size);
    u16* attn = sk;  // alias: sk dead after rowweight_kernel

    dim3 blk(256);

    // 1) mega-prep: f2bf + 5 weight transposes + pbprep
    prep_kernel<<<dim3(2337), blk, 0, stream>>>(x, xbf, Wq, WqT, Wkv, WkvT,
                                                Wsk, WskT, Wsq, WsqT, Wo, WoT,
                                                lng, lnb, Wp, Wg, SB);

    // 2) sk + sq projections in ONE dispatch (z=0: sk, z=1: sq via sBz offset)
    gemm_nt<64, 128, EpiSkSq><<<dim3(1, 512, 2), blk, 0, stream>>>(
        xbf, WskT, 0, 16384, 128, 128, 128, 0, EpiSkSq{sk, sq, bsk, bsq});
    rowweight_kernel<<<dim3(1024), blk, 0, stream>>>(sk, sq, w);

    // 3) pair-bias LN + projection -> pbd (fp32). BEFORE QKV: the 134 MB pair
    //    stream runs first, so Qw/Kp/Vt are L3-warm when dots/PV read them.
    pb_kernel<<<dim3(4096), blk, 0, stream>>>(pair, Wg, SB, pbd);

    // 4) fused Q+KV projection (N=1536, WqT||WkvT contiguous), r7 config
    //    (BM=128 — r8's BM=64 regressed) + XCD swizzle: Qw, Kp, Vt direct.
    gemm_nt<128, 128, EpiQKV><<<dim3(12, 256, 1), blk, 0, stream>>>(
        xbf, WqT, 0, 0, 128, 128, 128, 0, EpiQKV{bufA, bufB, Vt, w});

    // 5) dots[h] = Qw[h] @ Kp[h]^T + pb.  r7 config + XCD swizzle: each XCD
    //    owns one head's split-K chunks -> 2MB live panel set, L2-resident.
    if (useParts) {
        gemm_nt<128, 128, EpiDotsPart><<<dim3(4, 4, 32), blk, 0, stream>>>(
            bufA, bufB, 2097152, 2097152, 4096, 4096, 1024, 2, EpiDotsPart{pbd, parts});
        softmax_kernel<<<dim3(1024), blk, 0, stream>>>(pbd, parts, 3, attn);
    } else {
        // fallback (workspace too small): proven atomic split-K=8 path
        gemm_nt<128, 128, EpiDotsAtomic><<<dim3(4, 4, 64), blk, 0, stream>>>(
            bufA, bufB, 2097152, 2097152, 4096, 4096, 512, 3, EpiDotsAtomic{pbd});
        softmax_kernel<<<dim3(1024), blk, 0, stream>>>(pbd, pbd, 0, attn);
    }

    // 6) O[h] = attn[h] @ Vt[h]^T -> O2 (bufB, Kp dead). r7 config + XCD
    //    swizzle: one head per XCD (attn[h] 0.5MB + Vt[h] 4MB ~ L2).
    gemm_nt<128, 128, EpiPV><<<dim3(32, 4, 8), blk, 0, stream>>>(
        attn, Vt, 262144, 2097152, 512, 512, 512, 0, EpiPV{bufB});

    // 7) final projection: O2 @ Wo + bo -> out (fp32)
    gemm_nt<64, 128, EpiOut><<<dim3(1, 512, 1), blk, 0, stream>>>(
        bufB, WoT, 0, 0, 512, 512, 512, 0, EpiOut{out, bo});
}

// Round 10
// 353.362 us; speedup vs baseline: 1.0592x; 1.0355x over previous
//
#include <hip/hip_runtime.h>
#include <hip/hip_bf16.h>

typedef unsigned short u16;
typedef unsigned int u32;
typedef __attribute__((ext_vector_type(8))) short short8;
typedef __attribute__((ext_vector_type(4))) float floatx4;

__device__ inline float bf2f(u16 u) { union { u32 i; float f; } v; v.i = ((u32)u) << 16; return v.f; }
__device__ inline u16 f2bf(float f) {
    union { float f; u32 i; } v; v.f = f;
    u32 lsb = (v.i >> 16) & 1u;
    v.i += 0x7fffu + lsb;              // round-to-nearest-even
    return (u16)(v.i >> 16);
}

__device__ inline uint4 pack8(float4 a, float4 b) {
    uint4 q;
    q.x = (u32)f2bf(a.x) | ((u32)f2bf(a.y) << 16);
    q.y = (u32)f2bf(a.z) | ((u32)f2bf(a.w) << 16);
    q.z = (u32)f2bf(b.x) | ((u32)f2bf(b.y) << 16);
    q.w = (u32)f2bf(b.z) | ((u32)f2bf(b.w) << 16);
    return q;
}

__device__ inline void ld8(u16* dst, const float* src) {
    const float4 a = *(const float4*)src;
    const float4 b = *(const float4*)(src + 4);
    *(uint4*)dst = pack8(a, b);
}

// async 16B global->LDS DMA; ldst must be wave-uniform (dest = ldst + lane*16)
__device__ inline void async16(u16* ldst, const u16* gsrc) {
    __builtin_amdgcn_global_load_lds((const __attribute__((address_space(1))) u32*)gsrc,
                                     (__attribute__((address_space(3))) u32*)ldst, 16, 0, 0);
}

// counted vmcnt wait (never drain to 0 in the main loop - T4); "memory" clobber
// pins all memory ops (ds_read/global_load_lds) on the correct side.
template <int N> __device__ inline void waitvm() {
    static_assert(N == 0 || N == 2 || N == 3 || N == 4 || N == 6 || N == 8, "unsupported vmcnt");
    if constexpr (N == 0) asm volatile("s_waitcnt vmcnt(0)" ::: "memory");
    if constexpr (N == 2) asm volatile("s_waitcnt vmcnt(2)" ::: "memory");
    if constexpr (N == 3) asm volatile("s_waitcnt vmcnt(3)" ::: "memory");
    if constexpr (N == 4) asm volatile("s_waitcnt vmcnt(4)" ::: "memory");
    if constexpr (N == 6) asm volatile("s_waitcnt vmcnt(6)" ::: "memory");
    if constexpr (N == 8) asm volatile("s_waitcnt vmcnt(8)" ::: "memory");
}
__device__ inline void barrier_raw() {
    asm volatile("s_barrier" ::: "memory");
    __builtin_amdgcn_sched_barrier(0);      // pin schedule at the phase boundary
}
__device__ inline void waitlgkm0() {
    // rule #18: inline lgkmcnt wait must be followed by sched_barrier(0) or
    // hipcc may hoist register-only MFMAs above it (they ignore "memory").
    asm volatile("s_waitcnt lgkmcnt(0)" ::: "memory");
    __builtin_amdgcn_sched_barrier(0);
}

template <int BM, int BN, class Epi>
constexpr size_t gemm_lds_bytes() {
    size_t SLOT = (size_t)(BM * 32 + BN * 32);
    size_t RB = 2 * 3 * SLOT;
    size_t EBR = Epi::chunked ? 4 * 64 * (size_t)(BN + 4) : 0;
    size_t EBV = (Epi::chunked && Epi::kv) ? 4 * 128 * 68 : 0;
    size_t EB = EBR > EBV ? EBR : EBV;
    return RB > EB ? RB : EB;
}

// ---------------------------------------------------------------------------
// NT GEMM body: C[MxN] = A[MxK] @ B[NxK]^T, bf16 in / fp32 MFMA accum.
// 3-slot LDS ring, 2-ahead prefetch, counted vmcnt (T3/T4) — verified r5-r9.
//   prologue: stage(0), stage(1)
//   iter i:   s_waitcnt vmcnt(PW); s_barrier; stage(slot of i+2);
//             ds_read frags; lgkmcnt(0); MFMA on slot of i
//   tail:     vmcnt(PW) / vmcnt(0) peeled iters.
// Device function form: takes the LDS arena + linear block id + sub-grid
// geometry so it can be embedded in merged dispatches (block routing).
// Epi::xswz (T1, m204): bijective XCD-chunked remap of the linear id.
// Epilogue: chunked epis stage the fp32 C-tile through LDS in 64-row passes,
// emit 16-B coalesced chunks. Epi::kv: tiles with col0>=vbase stage TRANSPOSED
// (cs[col*68+row]) and emit j-contiguous chunks into Vt directly.
// Epi::ylim>=0: blocks with zh!=0 && by>=ylim exit early (sq fold).
// ---------------------------------------------------------------------------
template <int BM, int BN, class Epi>
__device__ __forceinline__ void gemm_body(char* smem, const u16* __restrict__ A, const u16* __restrict__ B,
                                          long sAz, long sBz, int lda, int ldb, int K, int zlog, Epi epi,
                                          int o, int gx, int gy, int gz)
{
    constexpr int AELE = BM * 32, BELE = BN * 32;   // elements per matrix per slot
    constexpr int SLOT = AELE + BELE;
    constexpr int IA = BM / 64, IB = BN / 64;       // DMA issues per wave per stage
    constexpr int PW = IA + IB;                      // vmcnt ops per wave per stage
    constexpr bool STAGE = Epi::chunked;
    static_assert(!STAGE || BN == 128, "chunked epilogue assumes BN=128");
    constexpr int LDC = BN + 4;                      // fp32 staging stride
    u16* lds = (u16*)smem;
    const int tid  = threadIdx.x;
    const int lane = tid & 63;
    const int wave = tid >> 6;

    int bx, by, bz;
    if constexpr (Epi::xswz) {                       // T1: XCD-chunked remap
        int n = gx * gy * gz;                        // launches guarantee n%8==0
        int wg = (o & 7) * (n >> 3) + (o >> 3);
        bx = wg % gx; int t = wg / gx; by = t % gy; bz = t / gy;
    } else {
        bx = o % gx; int t = o / gx; by = t % gy; bz = t / gy;
    }
    const int zh = bz >> zlog;
    const int zk = bz & ((1 << zlog) - 1);
    if constexpr (Epi::ylim >= 0) {                  // sq fold: skip unused blocks
        if (zh != 0 && by >= Epi::ylim) return;
    }
    const long row0 = (long)by * BM;
    const long col0 = (long)bx * BN;
    const u16* Ab = A + (long)zh * sAz + row0 * lda + (long)zk * K;
    const u16* Bb = B + (long)zh * sBz + col0 * ldb + (long)zk * K;
    constexpr int WM = BM / 2, WN = BN / 2, TM = WM / 16, TN = WN / 16;
    const int wm = (wave >> 1) * WM;
    const int wn = (wave & 1) * WN;
    const int l15 = lane & 15;
    const int quad = lane >> 4;
    const int swz = (l15 >> 1) & 3;   // (row>>1)&3 for row = 16*t + l15

    floatx4 acc[TM][TN];
#pragma unroll
    for (int i = 0; i < TM; i++)
#pragma unroll
        for (int j = 0; j < TN; j++) acc[i][j] = (floatx4){0.f, 0.f, 0.f, 0.f};

    auto stage = [&](int slot, int ki) {
        const int k0 = ki << 5;
        u16* base = lds + slot * SLOT;
#pragma unroll
        for (int i2 = 0; i2 < IA; i2++) {
            int s = wave * (IA * 64) + i2 * 64 + lane;       // chunk slot
            int r = s >> 2, c = (s & 3) ^ ((r >> 1) & 3);
            async16(base + (wave * (IA * 64) + i2 * 64) * 8, Ab + (long)r * lda + k0 + c * 8);
        }
        u16* bbase = base + AELE;
#pragma unroll
        for (int i2 = 0; i2 < IB; i2++) {
            int s = wave * (IB * 64) + i2 * 64 + lane;
            int r = s >> 2, c = (s & 3) ^ ((r >> 1) & 3);
            async16(bbase + (wave * (IB * 64) + i2 * 64) * 8, Bb + (long)r * ldb + k0 + c * 8);
        }
    };

    auto compute = [&](int slot) {
        const u16* As = lds + slot * SLOT;
        const u16* Bs = As + AELE;
        short8 af[TM], bfr[TN];
#pragma unroll
        for (int t = 0; t < TM; t++)
            af[t] = *(const short8*)(As + (wm + t * 16 + l15) * 32 + (quad ^ swz) * 8);
#pragma unroll
        for (int t = 0; t < TN; t++)
            bfr[t] = *(const short8*)(Bs + (wn + t * 16 + l15) * 32 + (quad ^ swz) * 8);
        waitlgkm0();                     // frag reads retired before next barrier
#pragma unroll
        for (int i = 0; i < TM; i++)
#pragma unroll
            for (int j = 0; j < TN; j++)
                acc[i][j] = __builtin_amdgcn_mfma_f32_16x16x32_bf16(af[i], bfr[j], acc[i][j], 0, 0, 0);
    };

    const int nIter = K >> 5;                        // K >= 128 -> nIter >= 4
    stage(0, 0);
    stage(1, 1);
    int s0 = 0, s1 = 1, s2 = 2;                      // slots of tiles i, i+1, i+2
    for (int i = 0; i + 2 < nIter; i++) {
        waitvm<PW>();
        barrier_raw();
        stage(s2, i + 2);                            // overwrites slot of tile i-1
        compute(s0);
        int t = s0; s0 = s1; s1 = s2; s2 = t;
    }
    waitvm<PW>(); barrier_raw(); compute(s0);
    waitvm<0>();  barrier_raw(); compute(s1);

    if constexpr (STAGE) {
        float* cs = (float*)smem;
        constexpr int NP = BM / 64;                  // 64-row passes
        bool vtile = false;
        if constexpr (Epi::kv) vtile = (col0 >= Epi::vbase);
#pragma unroll
        for (int p = 0; p < NP; p++) {
            __syncthreads();                         // prev reads done before overwrite
            if (!vtile) {
                if ((wm >> 6) == p) {
                    const int lr0 = wm & 63;
#pragma unroll
                    for (int i = 0; i < TM; i++)
#pragma unroll
                        for (int j = 0; j < TN; j++)
#pragma unroll
                            for (int r = 0; r < 4; r++)
                                cs[(lr0 + i * 16 + quad * 4 + r) * LDC + wn + j * 16 + l15] = acc[i][j][r];
                }
                __syncthreads();
                constexpr int CPT = (64 * BN) / (256 * 8);   // 16-B chunks per thread
#pragma unroll
                for (int k = 0; k < CPT; k++) {
                    int g = k * 256 + tid;
                    int row = g >> 4, c8 = (g & 15) * 8;
                    const float* pp = cs + row * LDC + c8;
                    float4 a = *(const float4*)pp;
                    float4 b = *(const float4*)(pp + 4);
                    epi.chunk(zh, zk, (int)row0 + p * 64 + row, (int)col0 + c8, a, b);
                }
            }
            if constexpr (Epi::kv) {
                if (vtile) {
                    // transposed staging: cs[col*68 + row], float4 per lane
                    if ((wm >> 6) == p) {
                        const int lr0 = wm & 63;
#pragma unroll
                        for (int i = 0; i < TM; i++)
#pragma unroll
                            for (int j = 0; j < TN; j++)
                                *(float4*)&cs[(wn + j * 16 + l15) * 68 + lr0 + i * 16 + quad * 4] =
                                    (float4){acc[i][j][0], acc[i][j][1], acc[i][j][2], acc[i][j][3]};
                    }
                    __syncthreads();
#pragma unroll
                    for (int k = 0; k < 4; k++) {    // 128 cols x 8 row-groups
                        int q = k * 256 + tid;
                        int colL = q >> 3, rg = q & 7;
                        const float* pp = cs + colL * 68 + rg * 8;
                        float4 a = *(const float4*)pp;
                        float4 b = *(const float4*)(pp + 4);
                        epi.vchunk(zh, (int)row0 + p * 64 + rg * 8, (int)col0 + colL, a, b);
                    }
                }
            }
        }
    } else {
#pragma unroll
        for (int i = 0; i < TM; i++)
#pragma unroll
            for (int j = 0; j < TN; j++)
#pragma unroll
                for (int r = 0; r < 4; r++) {
                    int row = (int)row0 + wm + i * 16 + quad * 4 + r;
                    int col = (int)col0 + wn + j * 16 + l15;
                    epi(zh, zk, row, col, acc[i][j][r]);
                }
    }
}

template <int BM, int BN, class Epi>
__global__ __launch_bounds__(256) void gemm_nt(const u16* __restrict__ A, const u16* __restrict__ B,
                                               long sAz, long sBz, int lda, int ldb, int K, int zlog, Epi epi)
{
    __shared__ __align__(16) char smem[gemm_lds_bytes<BM, BN, Epi>()];
    int o = ((int)blockIdx.z * gridDim.y + blockIdx.y) * gridDim.x + blockIdx.x;
    gemm_body<BM, BN, Epi>(smem, A, B, sAz, sBz, lda, ldb, K, zlog, epi,
                           o, gridDim.x, gridDim.y, gridDim.z);
}

// --- epilogues -------------------------------------------------------------
struct EpiSkSq {  // zh=0: sk = x@Wsk + bsk (rows 0..32767); zh=1: sq (rows 0..511)
    static constexpr bool chunked = true;
    static constexpr bool kv = false;
    static constexpr bool xswz = false;
    static constexpr int vbase = 0;
    static constexpr int ylim = 8;     // zh=1 uses only blocks y<8
    u16* sk; u16* sq; const float* bsk; const float* bsq;
    __device__ void chunk(int zh, int, int row, int col, float4 a, float4 b) const {
        const float* bias = zh ? bsq : bsk;
        u16* C = zh ? sq : sk;
        const float4* bp = (const float4*)(bias + col);
        float4 b0 = bp[0], b1 = bp[1];
        a.x += b0.x; a.y += b0.y; a.z += b0.z; a.w += b0.w;
        b.x += b1.x; b.y += b1.y; b.z += b1.z; b.w += b1.w;
        *(uint4*)(C + (long)row * 128 + col) = pack8(a, b);
    }
};
struct EpiQKV {  // fused Q+KV projection. cols: [0,512) Qw (w-scaled);
                 // [512,1024) Kp; [1024,1536) Vt via transposed vchunk.
    static constexpr bool chunked = true;
    static constexpr bool kv = true;
    static constexpr bool xswz = true;
    static constexpr int vbase = 1024;
    static constexpr int ylim = -1;
    u16* Qw; u16* Kp; u16* Vt; const float* w;
    __device__ void chunk(int, int, int row, int col, float4 a, float4 b) const {
        int r = row >> 9, i = row & 511;
        if (col < 512) {
            int h = col >> 6, d = col & 63;
            float s = w[((long)(i * 8 + h)) * 64 + r] * 0.125f;
            a.x *= s; a.y *= s; a.z *= s; a.w *= s;
            b.x *= s; b.y *= s; b.z *= s; b.w *= s;
            *(uint4*)(Qw + (long)h * 2097152 + (long)i * 4096 + r * 64 + d) = pack8(a, b);
        } else {
            int c = col - 512, h = c >> 6, d = c & 63;
            *(uint4*)(Kp + (long)h * 2097152 + (long)i * 4096 + r * 64 + d) = pack8(a, b);
        }
    }
    __device__ void vchunk(int, int row8, int col, float4 a, float4 b) const {
        // 8 packed values = global rows row8..row8+7 (same r, consecutive j)
        int r = row8 >> 9, j0 = row8 & 511;
        int c = col - vbase, h = c >> 6, d = c & 63;
        *(uint4*)(Vt + (long)h * 2097152 + ((long)r * 64 + d) * 512 + j0) = pack8(a, b);
    }
};
struct EpiDotsAtomic {  // fallback: dots[zh][row][col] += v (pb resident), fp32
    static constexpr bool chunked = false;
    static constexpr bool kv = false;
    static constexpr bool xswz = false;
    static constexpr int vbase = 0;
    static constexpr int ylim = -1;
    float* pbdots;
    __device__ void operator()(int zh, int, int row, int col, float v) const {
        atomicAdd(pbdots + (long)zh * 262144 + (long)row * 512 + col, v);
    }
};
struct EpiDotsPart {  // split-K, no atomics, CHUNKED (16-B stores): zk==0 folds
                      // into pbd via float4 RMW (unique owner per element);
                      // zk>=1 streams float4 to private partial buffers.
    static constexpr bool chunked = true;
    static constexpr bool kv = false;
    static constexpr bool xswz = true;
    static constexpr int vbase = 0;
    static constexpr int ylim = -1;
    float* pbd; float* parts;
    __device__ void chunk(int zh, int zk, int row, int col, float4 a, float4 b) const {
        long idx = (long)zh * 262144 + (long)row * 512 + col;
        if (zk == 0) {
            float4* p = (float4*)(pbd + idx);
            float4 p0 = p[0], p1 = p[1];
            p0.x += a.x; p0.y += a.y; p0.z += a.z; p0.w += a.w;
            p1.x += b.x; p1.y += b.y; p1.z += b.z; p1.w += b.w;
            p[0] = p0; p[1] = p1;
        } else {
            float4* p = (float4*)(parts + (long)(zk - 1) * 2097152 + idx);
            p[0] = a; p[1] = b;
        }
    }
};
struct EpiPV {  // rows=i, cols=(r,d), z=h -> O2[(r*512+i)][(h*64+d)] bf16
    static constexpr bool chunked = true;
    static constexpr bool kv = false;
    static constexpr bool xswz = true;
    static constexpr int vbase = 0;
    static constexpr int ylim = -1;
    u16* O2;
    __device__ void chunk(int zh, int, int row, int col, float4 a, float4 b) const {
        int r = col >> 6, d = col & 63;
        *(uint4*)(O2 + ((long)r * 512 + row) * 512 + zh * 64 + d) = pack8(a, b);
    }
};
struct EpiOut {  // final: out[row*128+col] = v + bo[col], fp32
    static constexpr bool chunked = true;
    static constexpr bool kv = false;
    static constexpr bool xswz = false;
    static constexpr int vbase = 0;
    static constexpr int ylim = -1;
    float* out; const float* bo;
    __device__ void chunk(int, int, int row, int col, float4 a, float4 b) const {
        const float4* bp = (const float4*)(bo + col);
        float4 b0 = bp[0], b1 = bp[1];
        a.x += b0.x; a.y += b0.y; a.z += b0.z; a.w += b0.w;
        b.x += b1.x; b.y += b1.y; b.z += b1.z; b.w += b1.w;
        float4* o = (float4*)(out + (long)row * 128 + col);
        o[0] = a; o[1] = b;
    }
};

// ---------------------------------------------------------------------------
// pair_bias LN + Linear(128->8) body, LDS-staged, coalesced. 64 rows/block.
// acc_h = rstd*(dot(v,Wg_h) - mu*S_h) + B_h.  Device-fn form: shares the LDS
// arena with gemm_body so it can be co-dispatched (block routing).
// LDS layout: Ls 64*132 f32 | sWg 1024 f32 | sSB 16 f32  (37952 B)
// ---------------------------------------------------------------------------
__device__ __forceinline__ void pb_body(char* smem, const float* __restrict__ pair,
                                        const float* __restrict__ Wg, const float* __restrict__ SB,
                                        float* __restrict__ pb, int bid)
{
    float* Ls  = (float*)smem;
    float* sWg = Ls + 64 * 132;
    float* sSB = sWg + 1024;
    int tid = threadIdx.x;
    for (int t = tid; t < 1024; t += 256) sWg[t] = Wg[t];
    if (tid < 16) sSB[tid] = SB[tid];
    long base = (long)bid * 8192;  // 64 rows * 128
    const float4* src = (const float4*)(pair + base);
#pragma unroll
    for (int k = 0; k < 8; k++) {
        int e = tid + k * 256;               // float4 index in tile, 0..2047
        float4 v = src[e];
        int r = e >> 5, c = (e & 31) << 2;
        *(float4*)(&Ls[r * 132 + c]) = v;
    }
    __syncthreads();
    int r = tid >> 2, sub = tid & 3;
    const float* row = &Ls[r * 132];
    float sum = 0.f, sqs = 0.f;
#pragma unroll
    for (int k = 0; k < 8; k++) {
        float4 v = *(const float4*)(&row[sub * 32 + k * 4]);
        sum += v.x + v.y + v.z + v.w;
        sqs += v.x * v.x + v.y * v.y + v.z * v.z + v.w * v.w;
    }
    sum += __shfl_xor(sum, 1); sqs += __shfl_xor(sqs, 1);
    sum += __shfl_xor(sum, 2); sqs += __shfl_xor(sqs, 2);
    float mu = sum * (1.f / 128.f);
    float var = sqs * (1.f / 128.f) - mu * mu;
    float rstd = rsqrtf(var + 1e-5f);
    int h0 = sub * 2;
    float a0 = 0.f, a1 = 0.f;
#pragma unroll
    for (int k = 0; k < 32; k++) {
        float4 v = *(const float4*)(&row[k * 4]);
        int c = k * 4;
        a0 += v.x * sWg[c * 8 + h0]     + v.y * sWg[(c + 1) * 8 + h0]
            + v.z * sWg[(c + 2) * 8 + h0] + v.w * sWg[(c + 3) * 8 + h0];
        a1 += v.x * sWg[c * 8 + h0 + 1]     + v.y * sWg[(c + 1) * 8 + h0 + 1]
            + v.z * sWg[(c + 2) * 8 + h0 + 1] + v.w * sWg[(c + 3) * 8 + h0 + 1];
    }
    long idx = (long)bid * 64 + r;
    pb[(long)h0 * 262144 + idx]       = rstd * (a0 - mu * sSB[h0])     + sSB[8 + h0];
    pb[(long)(h0 + 1) * 262144 + idx] = rstd * (a1 - mu * sSB[h0 + 1]) + sSB[8 + h0 + 1];
}

// ---------------------------------------------------------------------------
// Merged QKV-projection + pair-bias dispatch. Blocks [0,3072): the fused
// Q+KV GEMM (sub-grid 12x256, XCD-swizzled); blocks [3072,7168): pb LN+proj.
// The two halves are data-independent; co-dispatch overlaps pb's 134 MB
// BW-bound stream with the latency/MFMA-bound GEMM on the same CUs.
// Shared 48 KB LDS arena keeps both paths at 3 blocks/CU.
// ---------------------------------------------------------------------------
__global__ __launch_bounds__(256) void qkvpb_kernel(
    const u16* __restrict__ xbf, const u16* __restrict__ WqT,
    u16* Qw, u16* Kp, u16* Vt, const float* __restrict__ w,
    const float* __restrict__ pair, const float* __restrict__ Wg,
    const float* __restrict__ SB, float* __restrict__ pbd)
{
    constexpr size_t LB = gemm_lds_bytes<128, 128, EpiQKV>();   // 49152
    __shared__ __align__(16) char smem[LB];
    int gb = blockIdx.x;
    if (gb < 3072) {
        gemm_body<128, 128, EpiQKV>(smem, xbf, WqT, 0, 0, 128, 128, 128, 0,
                                    EpiQKV{Qw, Kp, Vt, w}, gb, 12, 256, 1);
    } else {
        pb_body(smem, pair, Wg, SB, pbd, gb - 3072);
    }
}

// ---------------------------------------------------------------------------
// 32x32 fp32->bf16 transpose tile (device helper for prep_kernel)
// ---------------------------------------------------------------------------
__device__ inline void trans_dev(const float* __restrict__ src, u16* __restrict__ dst,
                                 int R, int C, int bx, int by, int tid)
{
    __shared__ u16 t[32][33];
    int c0 = bx * 32, r0 = by * 32;
    int tx = tid & 31, ty = tid >> 5;   // 32 x 8
#pragma unroll
    for (int i = 0; i < 32; i += 8) t[ty + i][tx] = f2bf(src[(long)(r0 + ty + i) * C + c0 + tx]);
    __syncthreads();
#pragma unroll
    for (int i = 0; i < 32; i += 8) dst[(long)(c0 + ty + i) * R + r0 + tx] = t[tx][ty + i];
}

// ---------------------------------------------------------------------------
// Mega-prep: f2bf(x) + 5 weight transposes + pbprep in ONE dispatch.
// Block routing: [0,2048) f2bf; then 64 Wq, 128 Wkv, 16 Wsk, 16 Wsq, 64 Wo
// transpose tiles; final block = pbprep. Total 2337 blocks.
// ---------------------------------------------------------------------------
__global__ __launch_bounds__(256) void prep_kernel(
    const float* __restrict__ x, u16* __restrict__ xbf,
    const float* __restrict__ Wq, u16* __restrict__ WqT,
    const float* __restrict__ Wkv, u16* __restrict__ WkvT,
    const float* __restrict__ Wsk, u16* __restrict__ WskT,
    const float* __restrict__ Wsq, u16* __restrict__ WsqT,
    const float* __restrict__ Wo, u16* __restrict__ WoT,
    const float* __restrict__ g, const float* __restrict__ b,
    const float* __restrict__ Wp, float* __restrict__ Wg, float* __restrict__ SB)
{
    int gb = blockIdx.x, tid = threadIdx.x;
    if (gb < 2048) { long i = ((long)gb * 256 + tid) * 8; ld8(xbf + i, x + i); return; }
    gb -= 2048;
    if (gb < 64)  { trans_dev(Wq,  WqT,  128, 512,  gb & 15, gb >> 4, tid); return; }
    gb -= 64;
    if (gb < 128) { trans_dev(Wkv, WkvT, 128, 1024, gb & 31, gb >> 5, tid); return; }
    gb -= 128;
    if (gb < 16)  { trans_dev(Wsk, WskT, 128, 128,  gb & 3,  gb >> 2, tid); return; }
    gb -= 16;
    if (gb < 16)  { trans_dev(Wsq, WsqT, 128, 128,  gb & 3,  gb >> 2, tid); return; }
    gb -= 16;
    if (gb < 64)  { trans_dev(Wo,  WoT,  512, 128,  gb & 3,  gb >> 2, tid); return; }
    // final block: pbprep — Wg[c*8+h] = g[c]*Wp[c*8+h]; SB = {g.Wp, b.Wp}
    for (int t = tid; t < 1024; t += 256) Wg[t] = g[t >> 3] * Wp[t];
    if (tid < 16) {
        int h = tid & 7;
        const float* src = (tid < 8) ? g : b;
        float s = 0.f;
        for (int c = 0; c < 128; c++) s += src[c] * Wp[c * 8 + h];
        SB[tid] = s;
    }
}

// ---------------------------------------------------------------------------
// Tie-row weights: wave per (i,h); lane = r. logit = <sq[i,h,:],sk[r,i,h,:]>/4
// ---------------------------------------------------------------------------
__global__ __launch_bounds__(256) void rowweight_kernel(const u16* __restrict__ sk, const u16* __restrict__ sq,
                                                        float* __restrict__ w)
{
    int wid = blockIdx.x * 4 + (threadIdx.x >> 6);  // 0..4095 = i*8+h
    int lane = threadIdx.x & 63;                    // r
    int i = wid >> 3, h = wid & 7;
    const u16* sqp = sq + i * 128 + h * 16;
    const u16* skp = sk + ((long)lane * 512 + i) * 128 + h * 16;
    float dot = 0.f;
#pragma unroll
    for (int c = 0; c < 16; c++) dot += bf2f(sqp[c]) * bf2f(skp[c]);
    float logit = dot * 0.25f;
    float m = logit;
#pragma unroll
    for (int o = 32; o > 0; o >>= 1) m = fmaxf(m, __shfl_xor(m, o));
    float e = __expf(logit - m);
    float ssum = e;
#pragma unroll
    for (int o = 32; o > 0; o >>= 1) ssum += __shfl_xor(ssum, o);
    w[(long)wid * 64 + lane] = e / ssum;
}

// ---------------------------------------------------------------------------
// Row softmax over 512 cols; wave per row (h*512+i). fp32 in, bf16 out.
// np extra split-K partials are summed in before the softmax.
// ---------------------------------------------------------------------------
__global__ __launch_bounds__(256) void softmax_kernel(const float* __restrict__ dots,
                                                      const float* __restrict__ parts, int np,
                                                      u16* __restrict__ attn)
{
    int row = blockIdx.x * 4 + (threadIdx.x >> 6);
    int lane = threadIdx.x & 63;
    long base = (long)row * 512;
    const float* dp = dots + base;
    float v[8];
#pragma unroll
    for (int k = 0; k < 8; k++) v[k] = dp[k * 64 + lane];
    for (int t = 0; t < np; t++) {
        const float* pp = parts + (long)t * 2097152 + base;
#pragma unroll
        for (int k = 0; k < 8; k++) v[k] += pp[k * 64 + lane];
    }
    float m = v[0];
#pragma unroll
    for (int k = 1; k < 8; k++) m = fmaxf(m, v[k]);
#pragma unroll
    for (int o = 32; o > 0; o >>= 1) m = fmaxf(m, __shfl_xor(m, o));
    float s = 0.f;
#pragma unroll
    for (int k = 0; k < 8; k++) { v[k] = __expf(v[k] - m); s += v[k]; }
#pragma unroll
    for (int o = 32; o > 0; o >>= 1) s += __shfl_xor(s, o);
    float inv = 1.f / s;
    u16* ap = attn + (long)row * 512;
#pragma unroll
    for (int k = 0; k < 8; k++) ap[k * 64 + lane] = f2bf(v[k] * inv);
}

// ---------------------------------------------------------------------------
extern "C" void kernel_launch(void* const* d_in, const int* in_sizes, int n_in,
                              void* d_out, int out_size, void* d_ws, size_t ws_size,
                              hipStream_t stream)
{
    const float* x    = (const float*)d_in[0];
    const float* pair = (const float*)d_in[1];
    const float* Wq   = (const float*)d_in[2];
    const float* Wkv  = (const float*)d_in[3];
    const float* Wo   = (const float*)d_in[4];
    const float* bo   = (const float*)d_in[5];
    const float* lng  = (const float*)d_in[6];
    const float* lnb  = (const float*)d_in[7];
    const float* Wp   = (const float*)d_in[8];
    const float* Wsq  = (const float*)d_in[9];
    const float* bsq  = (const float*)d_in[10];
    const float* Wsk  = (const float*)d_in[11];
    const float* bsk  = (const float*)d_in[12];
    float* out = (float*)d_out;

    char* ws = (char*)d_ws;
    size_t off = 0;
    auto alloc = [&](size_t bytes) -> char* {
        char* p = ws + off; off += (bytes + 255) & ~(size_t)255; return p;
    };
    u16* WqT  = (u16*)alloc(512 * 128 * 2);     // WkvT MUST follow contiguously:
    u16* WkvT = (u16*)alloc(1024 * 128 * 2);    //   fused QKV uses B=WqT+col0*128
    u16* WskT = (u16*)alloc(128 * 128 * 2);     // WsqT MUST follow (sBz=16384)
    u16* WsqT = (u16*)alloc(128 * 128 * 2);
    u16* WoT  = (u16*)alloc(128 * 512 * 2);
    u16* xbf  = (u16*)alloc((size_t)32768 * 128 * 2);
    u16* sk   = (u16*)alloc((size_t)32768 * 128 * 2);   // later reused as attn
    u16* sq   = (u16*)alloc(512 * 128 * 2);
    float* w  = (float*)alloc((size_t)4096 * 64 * 4);
    float* Wg = (float*)alloc(1024 * 4);
    float* SB = (float*)alloc(16 * 4);
    u16* bufA = (u16*)alloc((size_t)8 * 512 * 4096 * 2);  // Qw
    u16* bufB = (u16*)alloc((size_t)8 * 512 * 4096 * 2);  // Kp, then O2
    u16* Vt   = (u16*)alloc((size_t)8 * 4096 * 512 * 2);
    float* pbd = (float*)alloc((size_t)8 * 512 * 512 * 4);  // pb, then dots (+partial 0)
    // allocated LAST so the atomic fallback still fits if ws is small:
    float* parts = (float*)alloc((size_t)3 * 2097152 * 4);  // split-K partials 1..3
    const bool useParts = (off <= ws_size);
    u16* attn = sk;  // alias: sk dead after rowweight_kernel

    dim3 blk(256);

    // 1) mega-prep: f2bf + 5 weight transposes + pbprep
    prep_kernel<<<dim3(2337), blk, 0, stream>>>(x, xbf, Wq, WqT, Wkv, WkvT,
                                                Wsk, WskT, Wsq, WsqT, Wo, WoT,
                                                lng, lnb, Wp, Wg, SB);

    // 2) sk + sq projections in ONE dispatch (z=0: sk, z=1: sq via sBz offset)
    gemm_nt<64, 128, EpiSkSq><<<dim3(1, 512, 2), blk, 0, stream>>>(
        xbf, WskT, 0, 16384, 128, 128, 128, 0, EpiSkSq{sk, sq, bsk, bsq});
    rowweight_kernel<<<dim3(1024), blk, 0, stream>>>(sk, sq, w);

    // 3) merged: fused Q+KV projection (blocks 0-3071, XCD-swizzled) +
    //    pair-bias LN/proj (blocks 3072-7167). Independent halves overlap:
    //    pb's BW-bound 134 MB stream hides under the latency-bound GEMM.
    qkvpb_kernel<<<dim3(7168), blk, 0, stream>>>(xbf, WqT, bufA, bufB, Vt, w,
                                                 pair, Wg, SB, pbd);

    // 4) dots[h] = Qw[h] @ Kp[h]^T + pb. split-K=4, no atomics, chunked
    //    16-B epilogue; XCD swizzle (each XCD owns one head's chunks).
    if (useParts) {
        gemm_nt<128, 128, EpiDotsPart><<<dim3(4, 4, 32), blk, 0, stream>>>(
            bufA, bufB, 2097152, 2097152, 4096, 4096, 1024, 2, EpiDotsPart{pbd, parts});
        softmax_kernel<<<dim3(1024), blk, 0, stream>>>(pbd, parts, 3, attn);
    } else {
        // fallback (workspace too small): proven atomic split-K=8 path
        gemm_nt<128, 128, EpiDotsAtomic><<<dim3(4, 4, 64), blk, 0, stream>>>(
            bufA, bufB, 2097152, 2097152, 4096, 4096, 512, 3, EpiDotsAtomic{pbd});
        softmax_kernel<<<dim3(1024), blk, 0, stream>>>(pbd, pbd, 0, attn);
    }

    // 5) O[h] = attn[h] @ Vt[h]^T -> O2 (bufB, Kp dead); XCD swizzle
    //    (one head per XCD: attn[h] 0.5MB + Vt[h] 4MB ~ L2).
    gemm_nt<128, 128, EpiPV><<<dim3(32, 4, 8), blk, 0, stream>>>(
        attn, Vt, 262144, 2097152, 512, 512, 512, 0, EpiPV{bufB});

    // 6) final projection: O2 @ Wo + bo -> out (fp32)
    gemm_nt<64, 128, EpiOut><<<dim3(1, 512, 1), blk, 0, stream>>>(
        bufB, WoT, 0, 0, 512, 512, 512, 0, EpiOut{out, bo});
}

// Round 12
// 352.886 us; speedup vs baseline: 1.0606x; 1.0013x over previous
//
#include <hip/hip_runtime.h>
#include <hip/hip_bf16.h>

typedef unsigned short u16;
typedef unsigned int u32;
typedef __attribute__((ext_vector_type(8))) short short8;
typedef __attribute__((ext_vector_type(4))) float floatx4;

__device__ inline float bf2f(u16 u) { union { u32 i; float f; } v; v.i = ((u32)u) << 16; return v.f; }
__device__ inline u16 f2bf(float f) {
    union { float f; u32 i; } v; v.f = f;
    u32 lsb = (v.i >> 16) & 1u;
    v.i += 0x7fffu + lsb;              // round-to-nearest-even
    return (u16)(v.i >> 16);
}

__device__ inline uint4 pack8(float4 a, float4 b) {
    uint4 q;
    q.x = (u32)f2bf(a.x) | ((u32)f2bf(a.y) << 16);
    q.y = (u32)f2bf(a.z) | ((u32)f2bf(a.w) << 16);
    q.z = (u32)f2bf(b.x) | ((u32)f2bf(b.y) << 16);
    q.w = (u32)f2bf(b.z) | ((u32)f2bf(b.w) << 16);
    return q;
}

__device__ inline void ld8(u16* dst, const float* src) {
    const float4 a = *(const float4*)src;
    const float4 b = *(const float4*)(src + 4);
    *(uint4*)dst = pack8(a, b);
}

// async 16B global->LDS DMA; ldst must be wave-uniform (dest = ldst + lane*16)
__device__ inline void async16(u16* ldst, const u16* gsrc) {
    __builtin_amdgcn_global_load_lds((const __attribute__((address_space(1))) u32*)gsrc,
                                     (__attribute__((address_space(3))) u32*)ldst, 16, 0, 0);
}

// counted vmcnt wait (never drain to 0 in the main loop - T4); "memory" clobber
// pins all memory ops (ds_read/global_load_lds) on the correct side.
template <int N> __device__ inline void waitvm() {
    static_assert(N == 0 || N == 2 || N == 3 || N == 4 || N == 6 || N == 8, "unsupported vmcnt");
    if constexpr (N == 0) asm volatile("s_waitcnt vmcnt(0)" ::: "memory");
    if constexpr (N == 2) asm volatile("s_waitcnt vmcnt(2)" ::: "memory");
    if constexpr (N == 3) asm volatile("s_waitcnt vmcnt(3)" ::: "memory");
    if constexpr (N == 4) asm volatile("s_waitcnt vmcnt(4)" ::: "memory");
    if constexpr (N == 6) asm volatile("s_waitcnt vmcnt(6)" ::: "memory");
    if constexpr (N == 8) asm volatile("s_waitcnt vmcnt(8)" ::: "memory");
}
__device__ inline void barrier_raw() {
    asm volatile("s_barrier" ::: "memory");
    __builtin_amdgcn_sched_barrier(0);      // pin schedule at the phase boundary
}
__device__ inline void waitlgkm0() {
    // rule #18: inline lgkmcnt wait must be followed by sched_barrier(0) or
    // hipcc may hoist register-only MFMAs above it (they ignore "memory").
    asm volatile("s_waitcnt lgkmcnt(0)" ::: "memory");
    __builtin_amdgcn_sched_barrier(0);
}

template <int BM, int BN, class Epi>
constexpr size_t gemm_lds_bytes() {
    size_t SLOT = (size_t)(BM * 32 + BN * 32);
    size_t RB = 2 * 3 * SLOT;
    size_t EBR = Epi::chunked ? 4 * 64 * (size_t)(BN + 4) : 0;
    size_t EBV = (Epi::chunked && Epi::kv) ? 4 * 128 * 68 : 0;
    size_t EB = EBR > EBV ? EBR : EBV;
    return RB > EB ? RB : EB;
}

// ---------------------------------------------------------------------------
// NT GEMM body: C[MxN] = A[MxK] @ B[NxK]^T, bf16 in / fp32 MFMA accum.
// 3-slot LDS ring, 2-ahead prefetch, counted vmcnt (T3/T4) — verified r5-r10.
//   prologue: stage(0), stage(1)
//   iter i:   s_waitcnt vmcnt(PW); s_barrier; stage(slot of i+2);
//             ds_read frags; lgkmcnt(0); MFMA on slot of i
//   tail:     vmcnt(PW) / vmcnt(0) peeled iters.
// Device function form: takes the LDS arena + linear block id + sub-grid
// geometry so it can be embedded in merged dispatches (block routing).
// Epi::xswz (T1, m204): bijective XCD-chunked remap of the linear id.
// Epilogue: chunked epis stage the fp32 C-tile through LDS in 64-row passes,
// emit 16-B coalesced chunks. Epi::kv: tiles with col0>=vbase stage TRANSPOSED
// (cs[col*68+row]) and emit j-contiguous chunks into Vt directly.
// Epi::ylim>=0: blocks with zh!=0 && by>=ylim exit early (sq fold).
// ---------------------------------------------------------------------------
template <int BM, int BN, class Epi>
__device__ __forceinline__ void gemm_body(char* smem, const u16* __restrict__ A, const u16* __restrict__ B,
                                          long sAz, long sBz, int lda, int ldb, int K, int zlog, Epi epi,
                                          int o, int gx, int gy, int gz)
{
    constexpr int AELE = BM * 32, BELE = BN * 32;   // elements per matrix per slot
    constexpr int SLOT = AELE + BELE;
    constexpr int IA = BM / 64, IB = BN / 64;       // DMA issues per wave per stage
    constexpr int PW = IA + IB;                      // vmcnt ops per wave per stage
    constexpr bool STAGE = Epi::chunked;
    static_assert(!STAGE || BN == 128, "chunked epilogue assumes BN=128");
    constexpr int LDC = BN + 4;                      // fp32 staging stride
    u16* lds = (u16*)smem;
    const int tid  = threadIdx.x;
    const int lane = tid & 63;
    const int wave = tid >> 6;

    int bx, by, bz;
    if constexpr (Epi::xswz) {                       // T1: XCD-chunked remap
        int n = gx * gy * gz;                        // launches guarantee n%8==0
        int wg = (o & 7) * (n >> 3) + (o >> 3);
        bx = wg % gx; int t = wg / gx; by = t % gy; bz = t / gy;
    } else {
        bx = o % gx; int t = o / gx; by = t % gy; bz = t / gy;
    }
    const int zh = bz >> zlog;
    const int zk = bz & ((1 << zlog) - 1);
    if constexpr (Epi::ylim >= 0) {                  // sq fold: skip unused blocks
        if (zh != 0 && by >= Epi::ylim) return;
    }
    const long row0 = (long)by * BM;
    const long col0 = (long)bx * BN;
    const u16* Ab = A + (long)zh * sAz + row0 * lda + (long)zk * K;
    const u16* Bb = B + (long)zh * sBz + col0 * ldb + (long)zk * K;
    constexpr int WM = BM / 2, WN = BN / 2, TM = WM / 16, TN = WN / 16;
    const int wm = (wave >> 1) * WM;
    const int wn = (wave & 1) * WN;
    const int l15 = lane & 15;
    const int quad = lane >> 4;
    const int swz = (l15 >> 1) & 3;   // (row>>1)&3 for row = 16*t + l15

    floatx4 acc[TM][TN];
#pragma unroll
    for (int i = 0; i < TM; i++)
#pragma unroll
        for (int j = 0; j < TN; j++) acc[i][j] = (floatx4){0.f, 0.f, 0.f, 0.f};

    auto stage = [&](int slot, int ki) {
        const int k0 = ki << 5;
        u16* base = lds + slot * SLOT;
#pragma unroll
        for (int i2 = 0; i2 < IA; i2++) {
            int s = wave * (IA * 64) + i2 * 64 + lane;       // chunk slot
            int r = s >> 2, c = (s & 3) ^ ((r >> 1) & 3);
            async16(base + (wave * (IA * 64) + i2 * 64) * 8, Ab + (long)r * lda + k0 + c * 8);
        }
        u16* bbase = base + AELE;
#pragma unroll
        for (int i2 = 0; i2 < IB; i2++) {
            int s = wave * (IB * 64) + i2 * 64 + lane;
            int r = s >> 2, c = (s & 3) ^ ((r >> 1) & 3);
            async16(bbase + (wave * (IB * 64) + i2 * 64) * 8, Bb + (long)r * ldb + k0 + c * 8);
        }
    };

    auto compute = [&](int slot) {
        const u16* As = lds + slot * SLOT;
        const u16* Bs = As + AELE;
        short8 af[TM], bfr[TN];
#pragma unroll
        for (int t = 0; t < TM; t++)
            af[t] = *(const short8*)(As + (wm + t * 16 + l15) * 32 + (quad ^ swz) * 8);
#pragma unroll
        for (int t = 0; t < TN; t++)
            bfr[t] = *(const short8*)(Bs + (wn + t * 16 + l15) * 32 + (quad ^ swz) * 8);
        waitlgkm0();                     // frag reads retired before next barrier
#pragma unroll
        for (int i = 0; i < TM; i++)
#pragma unroll
            for (int j = 0; j < TN; j++)
                acc[i][j] = __builtin_amdgcn_mfma_f32_16x16x32_bf16(af[i], bfr[j], acc[i][j], 0, 0, 0);
    };

    const int nIter = K >> 5;                        // K >= 128 -> nIter >= 4
    stage(0, 0);
    stage(1, 1);
    int s0 = 0, s1 = 1, s2 = 2;                      // slots of tiles i, i+1, i+2
    for (int i = 0; i + 2 < nIter; i++) {
        waitvm<PW>();
        barrier_raw();
        stage(s2, i + 2);                            // overwrites slot of tile i-1
        compute(s0);
        int t = s0; s0 = s1; s1 = s2; s2 = t;
    }
    waitvm<PW>(); barrier_raw(); compute(s0);
    waitvm<0>();  barrier_raw(); compute(s1);

    if constexpr (STAGE) {
        float* cs = (float*)smem;
        constexpr int NP = BM / 64;                  // 64-row passes
        bool vtile = false;
        if constexpr (Epi::kv) vtile = (col0 >= Epi::vbase);
#pragma unroll
        for (int p = 0; p < NP; p++) {
            __syncthreads();                         // prev reads done before overwrite
            if (!vtile) {
                if ((wm >> 6) == p) {
                    const int lr0 = wm & 63;
#pragma unroll
                    for (int i = 0; i < TM; i++)
#pragma unroll
                        for (int j = 0; j < TN; j++)
#pragma unroll
                            for (int r = 0; r < 4; r++)
                                cs[(lr0 + i * 16 + quad * 4 + r) * LDC + wn + j * 16 + l15] = acc[i][j][r];
                }
                __syncthreads();
                constexpr int CPT = (64 * BN) / (256 * 8);   // 16-B chunks per thread
#pragma unroll
                for (int k = 0; k < CPT; k++) {
                    int g = k * 256 + tid;
                    int row = g >> 4, c8 = (g & 15) * 8;
                    const float* pp = cs + row * LDC + c8;
                    float4 a = *(const float4*)pp;
                    float4 b = *(const float4*)(pp + 4);
                    epi.chunk(zh, zk, (int)row0 + p * 64 + row, (int)col0 + c8, a, b);
                }
            }
            if constexpr (Epi::kv) {
                if (vtile) {
                    // transposed staging: cs[col*68 + row], float4 per lane
                    if ((wm >> 6) == p) {
                        const int lr0 = wm & 63;
#pragma unroll
                        for (int i = 0; i < TM; i++)
#pragma unroll
                            for (int j = 0; j < TN; j++)
                                *(float4*)&cs[(wn + j * 16 + l15) * 68 + lr0 + i * 16 + quad * 4] =
                                    (float4){acc[i][j][0], acc[i][j][1], acc[i][j][2], acc[i][j][3]};
                    }
                    __syncthreads();
#pragma unroll
                    for (int k = 0; k < 4; k++) {    // 128 cols x 8 row-groups
                        int q = k * 256 + tid;
                        int colL = q >> 3, rg = q & 7;
                        const float* pp = cs + colL * 68 + rg * 8;
                        float4 a = *(const float4*)pp;
                        float4 b = *(const float4*)(pp + 4);
                        epi.vchunk(zh, (int)row0 + p * 64 + rg * 8, (int)col0 + colL, a, b);
                    }
                }
            }
        }
    } else {
#pragma unroll
        for (int i = 0; i < TM; i++)
#pragma unroll
            for (int j = 0; j < TN; j++)
#pragma unroll
                for (int r = 0; r < 4; r++) {
                    int row = (int)row0 + wm + i * 16 + quad * 4 + r;
                    int col = (int)col0 + wn + j * 16 + l15;
                    epi(zh, zk, row, col, acc[i][j][r]);
                }
    }
}

template <int BM, int BN, class Epi>
__global__ __launch_bounds__(256) void gemm_nt(const u16* __restrict__ A, const u16* __restrict__ B,
                                               long sAz, long sBz, int lda, int ldb, int K, int zlog, Epi epi)
{
    __shared__ __align__(16) char smem[gemm_lds_bytes<BM, BN, Epi>()];
    int o = ((int)blockIdx.z * gridDim.y + blockIdx.y) * gridDim.x + blockIdx.x;
    gemm_body<BM, BN, Epi>(smem, A, B, sAz, sBz, lda, ldb, K, zlog, epi,
                           o, gridDim.x, gridDim.y, gridDim.z);
}

// --- epilogues -------------------------------------------------------------
struct EpiSkSq {  // zh=0: sk = x@Wsk + bsk (rows 0..32767); zh=1: sq (rows 0..511)
    static constexpr bool chunked = true;
    static constexpr bool kv = false;
    static constexpr bool xswz = false;
    static constexpr int vbase = 0;
    static constexpr int ylim = 8;     // zh=1 uses only blocks y<8
    u16* sk; u16* sq; const float* bsk; const float* bsq;
    __device__ void chunk(int zh, int, int row, int col, float4 a, float4 b) const {
        const float* bias = zh ? bsq : bsk;
        u16* C = zh ? sq : sk;
        const float4* bp = (const float4*)(bias + col);
        float4 b0 = bp[0], b1 = bp[1];
        a.x += b0.x; a.y += b0.y; a.z += b0.z; a.w += b0.w;
        b.x += b1.x; b.y += b1.y; b.z += b1.z; b.w += b1.w;
        *(uint4*)(C + (long)row * 128 + col) = pack8(a, b);
    }
};
struct EpiQKV {  // fused Q+KV projection. cols: [0,512) Qw (w-scaled);
                 // [512,1024) Kp; [1024,1536) Vt via transposed vchunk.
    static constexpr bool chunked = true;
    static constexpr bool kv = true;
    static constexpr bool xswz = true;
    static constexpr int vbase = 1024;
    static constexpr int ylim = -1;
    u16* Qw; u16* Kp; u16* Vt; const float* w;
    __device__ void chunk(int, int, int row, int col, float4 a, float4 b) const {
        int r = row >> 9, i = row & 511;
        if (col < 512) {
            int h = col >> 6, d = col & 63;
            float s = w[((long)(i * 8 + h)) * 64 + r] * 0.125f;
            a.x *= s; a.y *= s; a.z *= s; a.w *= s;
            b.x *= s; b.y *= s; b.z *= s; b.w *= s;
            *(uint4*)(Qw + (long)h * 2097152 + (long)i * 4096 + r * 64 + d) = pack8(a, b);
        } else {
            int c = col - 512, h = c >> 6, d = c & 63;
            *(uint4*)(Kp + (long)h * 2097152 + (long)i * 4096 + r * 64 + d) = pack8(a, b);
        }
    }
    __device__ void vchunk(int, int row8, int col, float4 a, float4 b) const {
        // 8 packed values = global rows row8..row8+7 (same r, consecutive j)
        int r = row8 >> 9, j0 = row8 & 511;
        int c = col - vbase, h = c >> 6, d = c & 63;
        *(uint4*)(Vt + (long)h * 2097152 + ((long)r * 64 + d) * 512 + j0) = pack8(a, b);
    }
};
struct EpiDotsAtomic {  // fallback: dots[zh][row][col] += v (pb resident), fp32
    static constexpr bool chunked = false;
    static constexpr bool kv = false;
    static constexpr bool xswz = false;
    static constexpr int vbase = 0;
    static constexpr int ylim = -1;
    float* pbdots;
    __device__ void operator()(int zh, int, int row, int col, float v) const {
        atomicAdd(pbdots + (long)zh * 262144 + (long)row * 512 + col, v);
    }
};
struct EpiDotsPart {  // split-K, no atomics, CHUNKED (16-B stores): zk==0 folds
                      // into pbd via float4 RMW (unique owner per element);
                      // zk>=1 streams float4 to private partial buffers.
    static constexpr bool chunked = true;
    static constexpr bool kv = false;
    static constexpr bool xswz = true;
    static constexpr int vbase = 0;
    static constexpr int ylim = -1;
    float* pbd; float* parts;
    __device__ void chunk(int zh, int zk, int row, int col, float4 a, float4 b) const {
        long idx = (long)zh * 262144 + (long)row * 512 + col;
        if (zk == 0) {
            float4* p = (float4*)(pbd + idx);
            float4 p0 = p[0], p1 = p[1];
            p0.x += a.x; p0.y += a.y; p0.z += a.z; p0.w += a.w;
            p1.x += b.x; p1.y += b.y; p1.z += b.z; p1.w += b.w;
            p[0] = p0; p[1] = p1;
        } else {
            float4* p = (float4*)(parts + (long)(zk - 1) * 2097152 + idx);
            p[0] = a; p[1] = b;
        }
    }
};
struct EpiPV {  // rows=i, cols=(r,d), z=h -> O2[(r*512+i)][(h*64+d)] bf16
    static constexpr bool chunked = true;
    static constexpr bool kv = false;
    static constexpr bool xswz = true;
    static constexpr int vbase = 0;
    static constexpr int ylim = -1;
    u16* O2;
    __device__ void chunk(int zh, int, int row, int col, float4 a, float4 b) const {
        int r = col >> 6, d = col & 63;
        *(uint4*)(O2 + ((long)r * 512 + row) * 512 + zh * 64 + d) = pack8(a, b);
    }
};
struct EpiOut {  // final: out[row*128+col] = v + bo[col], fp32
    static constexpr bool chunked = true;
    static constexpr bool kv = false;
    static constexpr bool xswz = false;
    static constexpr int vbase = 0;
    static constexpr int ylim = -1;
    float* out; const float* bo;
    __device__ void chunk(int, int, int row, int col, float4 a, float4 b) const {
        const float4* bp = (const float4*)(bo + col);
        float4 b0 = bp[0], b1 = bp[1];
        a.x += b0.x; a.y += b0.y; a.z += b0.z; a.w += b0.w;
        b.x += b1.x; b.y += b1.y; b.z += b1.z; b.w += b1.w;
        float4* o = (float4*)(out + (long)row * 128 + col);
        o[0] = a; o[1] = b;
    }
};

// ---------------------------------------------------------------------------
// pair_bias LN + Linear(128->8) body, LDS-staged, coalesced. 64 rows/block.
// acc_h = rstd*(dot(v,Wg_h) - mu*S_h) + B_h.  Device-fn form: shares the LDS
// arena with gemm_body so it can be co-dispatched (block routing).
// LDS layout: Ls 64*132 f32 | sWg 1024 f32 | sSB 16 f32  (37952 B)
// ---------------------------------------------------------------------------
__device__ __forceinline__ void pb_body(char* smem, const float* __restrict__ pair,
                                        const float* __restrict__ Wg, const float* __restrict__ SB,
                                        float* __restrict__ pb, int bid)
{
    float* Ls  = (float*)smem;
    float* sWg = Ls + 64 * 132;
    float* sSB = sWg + 1024;
    int tid = threadIdx.x;
    for (int t = tid; t < 1024; t += 256) sWg[t] = Wg[t];
    if (tid < 16) sSB[tid] = SB[tid];
    long base = (long)bid * 8192;  // 64 rows * 128
    const float4* src = (const float4*)(pair + base);
#pragma unroll
    for (int k = 0; k < 8; k++) {
        int e = tid + k * 256;               // float4 index in tile, 0..2047
        float4 v = src[e];
        int r = e >> 5, c = (e & 31) << 2;
        *(float4*)(&Ls[r * 132 + c]) = v;
    }
    __syncthreads();
    int r = tid >> 2, sub = tid & 3;
    const float* row = &Ls[r * 132];
    float sum = 0.f, sqs = 0.f;
#pragma unroll
    for (int k = 0; k < 8; k++) {
        float4 v = *(const float4*)(&row[sub * 32 + k * 4]);
        sum += v.x + v.y + v.z + v.w;
        sqs += v.x * v.x + v.y * v.y + v.z * v.z + v.w * v.w;
    }
    sum += __shfl_xor(sum, 1); sqs += __shfl_xor(sqs, 1);
    sum += __shfl_xor(sum, 2); sqs += __shfl_xor(sqs, 2);
    float mu = sum * (1.f / 128.f);
    float var = sqs * (1.f / 128.f) - mu * mu;
    float rstd = rsqrtf(var + 1e-5f);
    int h0 = sub * 2;
    float a0 = 0.f, a1 = 0.f;
#pragma unroll
    for (int k = 0; k < 32; k++) {
        float4 v = *(const float4*)(&row[k * 4]);
        int c = k * 4;
        a0 += v.x * sWg[c * 8 + h0]     + v.y * sWg[(c + 1) * 8 + h0]
            + v.z * sWg[(c + 2) * 8 + h0] + v.w * sWg[(c + 3) * 8 + h0];
        a1 += v.x * sWg[c * 8 + h0 + 1]     + v.y * sWg[(c + 1) * 8 + h0 + 1]
            + v.z * sWg[(c + 2) * 8 + h0 + 1] + v.w * sWg[(c + 3) * 8 + h0 + 1];
    }
    long idx = (long)bid * 64 + r;
    pb[(long)h0 * 262144 + idx]       = rstd * (a0 - mu * sSB[h0])     + sSB[8 + h0];
    pb[(long)(h0 + 1) * 262144 + idx] = rstd * (a1 - mu * sSB[h0 + 1]) + sSB[8 + h0 + 1];
}

// ---------------------------------------------------------------------------
// Merged QKV-projection + pair-bias dispatch, INTERLEAVED routing: each run
// of 7 consecutive block ids carries 3 QKV-GEMM blocks + 4 pb blocks
// (7168 = 7*1024; QKV gets 3072, pb gets 4096). In-order dispatch therefore
// fills every CU with a MIX of latency/MFMA-bound GEMM blocks and BW-bound
// pb blocks from cycle 0 — r10's sequential routing (gb<3072) ran the halves
// back-to-back (88 us, HBM 26%, MfmaUtil 5.7%: neither pipe fed).
// Shared 48 KB LDS arena keeps both paths at 3 blocks/CU.
// ---------------------------------------------------------------------------
__global__ __launch_bounds__(256) void qkvpb_kernel(
    const u16* __restrict__ xbf, const u16* __restrict__ WqT,
    u16* Qw, u16* Kp, u16* Vt, const float* __restrict__ w,
    const float* __restrict__ pair, const float* __restrict__ Wg,
    const float* __restrict__ SB, float* __restrict__ pbd)
{
    constexpr size_t LB = gemm_lds_bytes<128, 128, EpiQKV>();   // 49152
    __shared__ __align__(16) char smem[LB];
    int gb = blockIdx.x;
    int r7 = gb % 7, q7 = gb / 7;
    if (r7 < 3) {
        gemm_body<128, 128, EpiQKV>(smem, xbf, WqT, 0, 0, 128, 128, 128, 0,
                                    EpiQKV{Qw, Kp, Vt, w}, q7 * 3 + r7, 12, 256, 1);
    } else {
        pb_body(smem, pair, Wg, SB, pbd, q7 * 4 + (r7 - 3));
    }
}

// ---------------------------------------------------------------------------
// 32x32 fp32->bf16 transpose tile (device helper for prep_kernel)
// ---------------------------------------------------------------------------
__device__ inline void trans_dev(const float* __restrict__ src, u16* __restrict__ dst,
                                 int R, int C, int bx, int by, int tid)
{
    __shared__ u16 t[32][33];
    int c0 = bx * 32, r0 = by * 32;
    int tx = tid & 31, ty = tid >> 5;   // 32 x 8
#pragma unroll
    for (int i = 0; i < 32; i += 8) t[ty + i][tx] = f2bf(src[(long)(r0 + ty + i) * C + c0 + tx]);
    __syncthreads();
#pragma unroll
    for (int i = 0; i < 32; i += 8) dst[(long)(c0 + ty + i) * R + r0 + tx] = t[tx][ty + i];
}

// ---------------------------------------------------------------------------
// Mega-prep: f2bf(x) + 5 weight transposes + pbprep in ONE dispatch.
// Block routing: [0,2048) f2bf; then 64 Wq, 128 Wkv, 16 Wsk, 16 Wsq, 64 Wo
// transpose tiles; final block = pbprep. Total 2337 blocks.
// ---------------------------------------------------------------------------
__global__ __launch_bounds__(256) void prep_kernel(
    const float* __restrict__ x, u16* __restrict__ xbf,
    const float* __restrict__ Wq, u16* __restrict__ WqT,
    const float* __restrict__ Wkv, u16* __restrict__ WkvT,
    const float* __restrict__ Wsk, u16* __restrict__ WskT,
    const float* __restrict__ Wsq, u16* __restrict__ WsqT,
    const float* __restrict__ Wo, u16* __restrict__ WoT,
    const float* __restrict__ g, const float* __restrict__ b,
    const float* __restrict__ Wp, float* __restrict__ Wg, float* __restrict__ SB)
{
    int gb = blockIdx.x, tid = threadIdx.x;
    if (gb < 2048) { long i = ((long)gb * 256 + tid) * 8; ld8(xbf + i, x + i); return; }
    gb -= 2048;
    if (gb < 64)  { trans_dev(Wq,  WqT,  128, 512,  gb & 15, gb >> 4, tid); return; }
    gb -= 64;
    if (gb < 128) { trans_dev(Wkv, WkvT, 128, 1024, gb & 31, gb >> 5, tid); return; }
    gb -= 128;
    if (gb < 16)  { trans_dev(Wsk, WskT, 128, 128,  gb & 3,  gb >> 2, tid); return; }
    gb -= 16;
    if (gb < 16)  { trans_dev(Wsq, WsqT, 128, 128,  gb & 3,  gb >> 2, tid); return; }
    gb -= 16;
    if (gb < 64)  { trans_dev(Wo,  WoT,  512, 128,  gb & 3,  gb >> 2, tid); return; }
    // final block: pbprep — Wg[c*8+h] = g[c]*Wp[c*8+h]; SB = {g.Wp, b.Wp}
    for (int t = tid; t < 1024; t += 256) Wg[t] = g[t >> 3] * Wp[t];
    if (tid < 16) {
        int h = tid & 7;
        const float* src = (tid < 8) ? g : b;
        float s = 0.f;
        for (int c = 0; c < 128; c++) s += src[c] * Wp[c * 8 + h];
        SB[tid] = s;
    }
}

// ---------------------------------------------------------------------------
// Tie-row weights: wave per (i,h); lane = r. logit = <sq[i,h,:],sk[r,i,h,:]>/4
// ---------------------------------------------------------------------------
__global__ __launch_bounds__(256) void rowweight_kernel(const u16* __restrict__ sk, const u16* __restrict__ sq,
                                                        float* __restrict__ w)
{
    int wid = blockIdx.x * 4 + (threadIdx.x >> 6);  // 0..4095 = i*8+h
    int lane = threadIdx.x & 63;                    // r
    int i = wid >> 3, h = wid & 7;
    const u16* sqp = sq + i * 128 + h * 16;
    const u16* skp = sk + ((long)lane * 512 + i) * 128 + h * 16;
    float dot = 0.f;
#pragma unroll
    for (int c = 0; c < 16; c++) dot += bf2f(sqp[c]) * bf2f(skp[c]);
    float logit = dot * 0.25f;
    float m = logit;
#pragma unroll
    for (int o = 32; o > 0; o >>= 1) m = fmaxf(m, __shfl_xor(m, o));
    float e = __expf(logit - m);
    float ssum = e;
#pragma unroll
    for (int o = 32; o > 0; o >>= 1) ssum += __shfl_xor(ssum, o);
    w[(long)wid * 64 + lane] = e / ssum;
}

// ---------------------------------------------------------------------------
// Row softmax over 512 cols; wave per row (h*512+i). fp32 in, bf16 out.
// np extra split-K partials are summed in before the softmax.
// ---------------------------------------------------------------------------
__global__ __launch_bounds__(256) void softmax_kernel(const float* __restrict__ dots,
                                                      const float* __restrict__ parts, int np,
                                                      u16* __restrict__ attn)
{
    int row = blockIdx.x * 4 + (threadIdx.x >> 6);
    int lane = threadIdx.x & 63;
    long base = (long)row * 512;
    const float* dp = dots + base;
    float v[8];
#pragma unroll
    for (int k = 0; k < 8; k++) v[k] = dp[k * 64 + lane];
    for (int t = 0; t < np; t++) {
        const float* pp = parts + (long)t * 2097152 + base;
#pragma unroll
        for (int k = 0; k < 8; k++) v[k] += pp[k * 64 + lane];
    }
    float m = v[0];
#pragma unroll
    for (int k = 1; k < 8; k++) m = fmaxf(m, v[k]);
#pragma unroll
    for (int o = 32; o > 0; o >>= 1) m = fmaxf(m, __shfl_xor(m, o));
    float s = 0.f;
#pragma unroll
    for (int k = 0; k < 8; k++) { v[k] = __expf(v[k] - m); s += v[k]; }
#pragma unroll
    for (int o = 32; o > 0; o >>= 1) s += __shfl_xor(s, o);
    float inv = 1.f / s;
    u16* ap = attn + (long)row * 512;
#pragma unroll
    for (int k = 0; k < 8; k++) ap[k * 64 + lane] = f2bf(v[k] * inv);
}

// ---------------------------------------------------------------------------
extern "C" void kernel_launch(void* const* d_in, const int* in_sizes, int n_in,
                              void* d_out, int out_size, void* d_ws, size_t ws_size,
                              hipStream_t stream)
{
    const float* x    = (const float*)d_in[0];
    const float* pair = (const float*)d_in[1];
    const float* Wq   = (const float*)d_in[2];
    const float* Wkv  = (const float*)d_in[3];
    const float* Wo   = (const float*)d_in[4];
    const float* bo   = (const float*)d_in[5];
    const float* lng  = (const float*)d_in[6];
    const float* lnb  = (const float*)d_in[7];
    const float* Wp   = (const float*)d_in[8];
    const float* Wsq  = (const float*)d_in[9];
    const float* bsq  = (const float*)d_in[10];
    const float* Wsk  = (const float*)d_in[11];
    const float* bsk  = (const float*)d_in[12];
    float* out = (float*)d_out;

    char* ws = (char*)d_ws;
    size_t off = 0;
    auto alloc = [&](size_t bytes) -> char* {
        char* p = ws + off; off += (bytes + 255) & ~(size_t)255; return p;
    };
    u16* WqT  = (u16*)alloc(512 * 128 * 2);     // WkvT MUST follow contiguously:
    u16* WkvT = (u16*)alloc(1024 * 128 * 2);    //   fused QKV uses B=WqT+col0*128
    u16* WskT = (u16*)alloc(128 * 128 * 2);     // WsqT MUST follow (sBz=16384)
    u16* WsqT = (u16*)alloc(128 * 128 * 2);
    u16* WoT  = (u16*)alloc(128 * 512 * 2);
    u16* xbf  = (u16*)alloc((size_t)32768 * 128 * 2);
    u16* sk   = (u16*)alloc((size_t)32768 * 128 * 2);   // later reused as attn
    u16* sq   = (u16*)alloc(512 * 128 * 2);
    float* w  = (float*)alloc((size_t)4096 * 64 * 4);
    float* Wg = (float*)alloc(1024 * 4);
    float* SB = (float*)alloc(16 * 4);
    u16* bufA = (u16*)alloc((size_t)8 * 512 * 4096 * 2);  // Qw
    u16* bufB = (u16*)alloc((size_t)8 * 512 * 4096 * 2);  // Kp, then O2
    u16* Vt   = (u16*)alloc((size_t)8 * 4096 * 512 * 2);
    float* pbd = (float*)alloc((size_t)8 * 512 * 512 * 4);  // pb, then dots (+partial 0)
    // allocated LAST so the atomic fallback still fits if ws is small:
    float* parts = (float*)alloc((size_t)3 * 2097152 * 4);  // split-K partials 1..3
    const bool useParts = (off <= ws_size);
    u16* attn = sk;  // alias: sk dead after rowweight_kernel

    dim3 blk(256);

    // 1) mega-prep: f2bf + 5 weight transposes + pbprep
    prep_kernel<<<dim3(2337), blk, 0, stream>>>(x, xbf, Wq, WqT, Wkv, WkvT,
                                                Wsk, WskT, Wsq, WsqT, Wo, WoT,
                                                lng, lnb, Wp, Wg, SB);

    // 2) sk + sq projections in ONE dispatch (z=0: sk, z=1: sq via sBz offset)
    gemm_nt<64, 128, EpiSkSq><<<dim3(1, 512, 2), blk, 0, stream>>>(
        xbf, WskT, 0, 16384, 128, 128, 128, 0, EpiSkSq{sk, sq, bsk, bsq});
    rowweight_kernel<<<dim3(1024), blk, 0, stream>>>(sk, sq, w);

    // 3) merged + INTERLEAVED: fused Q+KV projection (3072 blocks) + pair-bias
    //    LN/proj (4096 blocks), 3:4 mix per 7 ids -> both pipes fed from t=0.
    qkvpb_kernel<<<dim3(7168), blk, 0, stream>>>(xbf, WqT, bufA, bufB, Vt, w,
                                                 pair, Wg, SB, pbd);

    // 4) dots[h] = Qw[h] @ Kp[h]^T + pb. split-K=4, no atomics, chunked
    //    16-B epilogue; XCD swizzle (each XCD owns one head's chunks).
    if (useParts) {
        gemm_nt<128, 128, EpiDotsPart><<<dim3(4, 4, 32), blk, 0, stream>>>(
            bufA, bufB, 2097152, 2097152, 4096, 4096, 1024, 2, EpiDotsPart{pbd, parts});
        softmax_kernel<<<dim3(1024), blk, 0, stream>>>(pbd, parts, 3, attn);
    } else {
        // fallback (workspace too small): proven atomic split-K=8 path
        gemm_nt<128, 128, EpiDotsAtomic><<<dim3(4, 4, 64), blk, 0, stream>>>(
            bufA, bufB, 2097152, 2097152, 4096, 4096, 512, 3, EpiDotsAtomic{pbd});
        softmax_kernel<<<dim3(1024), blk, 0, stream>>>(pbd, pbd, 0, attn);
    }

    // 5) O[h] = attn[h] @ Vt[h]^T -> O2 (bufB, Kp dead); XCD swizzle
    //    (one head per XCD: attn[h] 0.5MB + Vt[h] 4MB ~ L2).
    gemm_nt<128, 128, EpiPV><<<dim3(32, 4, 8), blk, 0, stream>>>(
        attn, Vt, 262144, 2097152, 512, 512, 512, 0, EpiPV{bufB});

    // 6) final projection: O2 @ Wo + bo -> out (fp32)
    gemm_nt<64, 128, EpiOut><<<dim3(1, 512, 1), blk, 0, stream>>>(
        bufB, WoT, 0, 0, 512, 512, 512, 0, EpiOut{out, bo});
}